// Round 2
// baseline (160.322 us; speedup 1.0000x reference)
//
#include <hip/hip_runtime.h>

#define TSIZE 512
#define NT 512
#define EPSV 1e-9f

// One thread per pixel; triangles processed in order (painter + z>=).
// All float math in the classification/interp chain uses __f*_rn to match
// numpy's per-op rounding (no FMA contraction, same association order).
// Round 1 resubmit: prior round failed on container infra, not the kernel.
__global__ __launch_bounds__(256) void render_kernel(const float* __restrict__ tris,
                                                     float4* __restrict__ out) {
  __shared__ float sf[10 * NT];            // 9 vertex comps + ws  (20 KB)
  __shared__ unsigned short sb[4 * NT];    // xmin,xmax,ymin,ymax  (4 KB)
  __shared__ float s_zred[4];

  const int tid = threadIdx.x;

  // --- per-triangle setup (each block redundantly; cheap) ---
  for (int t = tid; t < NT; t += 256) {
    const float* tp = tris + t * 9;
    float v0x = tp[0], v0y = tp[1], v0z = tp[2];
    float v1x = tp[3], v1y = tp[4], v1z = tp[5];
    float v2x = tp[6], v2y = tp[7], v2z = tp[8];
    sf[0*NT+t] = v0x; sf[1*NT+t] = v0y; sf[2*NT+t] = v0z;
    sf[3*NT+t] = v1x; sf[4*NT+t] = v1y; sf[5*NT+t] = v1z;
    sf[6*NT+t] = v2x; sf[7*NT+t] = v2y; sf[8*NT+t] = v2z;
    // w = (v1x-v0x)*(v2y-v0y) - (v1y-v0y)*(v2x-v0x), numpy op order
    float w = __fsub_rn(__fmul_rn(__fsub_rn(v1x,v0x), __fsub_rn(v2y,v0y)),
                        __fmul_rn(__fsub_rn(v1y,v0y), __fsub_rn(v2x,v0x)));
    bool valid = (w >= EPSV);
    sf[9*NT+t] = valid ? w : 1.0f;
    int xmn = 0, xmx = 0, ymn = 0, ymx = 0;
    if (valid) {
      float bxn = fminf(v0x, fminf(v1x, v2x));
      float byn = fminf(v0y, fminf(v1y, v2y));
      float bxx = fmaxf(v0x, fmaxf(v1x, v2x));
      float byx = fmaxf(v0y, fmaxf(v1y, v2y));
      xmn = (int)floorf(__fmul_rn(__fadd_rn(fminf(fmaxf(bxn,-1.0f),1.0f),1.0f),256.0f));
      ymn = (int)floorf(__fmul_rn(__fadd_rn(fminf(fmaxf(byn,-1.0f),1.0f),1.0f),256.0f));
      xmx = (int)floorf(__fmul_rn(__fadd_rn(fminf(fmaxf(bxx,-1.0f),1.0f),1.0f),256.0f));
      ymx = (int)floorf(__fmul_rn(__fadd_rn(fminf(fmaxf(byx,-1.0f),1.0f),1.0f),256.0f));
    }
    sb[0*NT+t] = (unsigned short)xmn;
    sb[1*NT+t] = (unsigned short)xmx;
    sb[2*NT+t] = (unsigned short)ymn;
    sb[3*NT+t] = (unsigned short)ymx;
  }

  // --- zmin over all 1536 vertex z values (min is order-independent) ---
  float zm = 3.4e38f;
  for (int v = tid; v < NT * 3; v += 256) zm = fminf(zm, tris[v * 3 + 2]);
  for (int off = 32; off > 0; off >>= 1) zm = fminf(zm, __shfl_down(zm, off, 64));
  if ((tid & 63) == 0) s_zred[tid >> 6] = zm;
  __syncthreads();   // also fences sf/sb setup
  zm = fminf(fminf(s_zred[0], s_zred[1]), fminf(s_zred[2], s_zred[3]));

  // --- per-pixel triangle loop ---
  const int pid = blockIdx.x * 256 + tid;
  const int i = pid >> 9;            // block-uniform (256 | 512)
  const int j = pid & (TSIZE - 1);
  const float delta = 2.0f / 511.0f; // f32 compile-time constant, = jnp linspace step
  const float px = __fadd_rn(-1.0f, __fmul_rn((float)i, delta));
  const float py = __fadd_rn(-1.0f, __fmul_rn((float)j, delta));

  float zb = zm;
  float rx = 0.0f, ry = 0.0f, rz = 0.0f, ra = 0.0f;

  for (int t = 0; t < NT; ++t) {
    int xmn = sb[0*NT+t], xmx = sb[1*NT+t];
    int ymn = sb[2*NT+t], ymx = sb[3*NT+t];
    if (i < xmn || i >= xmx || j < ymn || j >= ymx) continue;

    float v0x = sf[0*NT+t], v0y = sf[1*NT+t];
    float v1x = sf[3*NT+t], v1y = sf[4*NT+t];
    float v2x = sf[6*NT+t], v2y = sf[7*NT+t];
    // edge functions, numpy op order: (b.x-a.x)*(c.y-a.y) - (b.y-a.y)*(c.x-a.x)
    float pAB = __fsub_rn(__fmul_rn(__fsub_rn(px,v1x), __fsub_rn(v0y,v1y)),
                          __fmul_rn(__fsub_rn(py,v1y), __fsub_rn(v0x,v1x)));
    float pCB = __fsub_rn(__fmul_rn(__fsub_rn(px,v2x), __fsub_rn(v1y,v2y)),
                          __fmul_rn(__fsub_rn(py,v2y), __fsub_rn(v1x,v2x)));
    float pCA = __fsub_rn(__fmul_rn(__fsub_rn(px,v0x), __fsub_rn(v2y,v0y)),
                          __fmul_rn(__fsub_rn(py,v0y), __fsub_rn(v2x,v0x)));
    float prod = __fmul_rn(__fmul_rn(fmaxf(pAB,0.0f), fmaxf(pCB,0.0f)), fmaxf(pCA,0.0f));
    if (prod > 0.0f) {
      float ws = sf[9*NT+t];
      float w1 = __fdiv_rn(pCB, ws);
      float w2 = __fdiv_rn(pCA, ws);
      float w3 = __fsub_rn(__fsub_rn(1.0f, w1), w2);
      float v0z = sf[2*NT+t], v1z = sf[5*NT+t], v2z = sf[8*NT+t];
      float pz = __fadd_rn(__fadd_rn(__fmul_rn(w1,v0z), __fmul_rn(w2,v1z)),
                           __fmul_rn(w3,v2z));
      if (pz >= zb) {
        zb = pz;
        rx = __fadd_rn(__fadd_rn(__fmul_rn(w1,v0x), __fmul_rn(w2,v1x)),
                       __fmul_rn(w3,v2x));
        ry = __fadd_rn(__fadd_rn(__fmul_rn(w1,v0y), __fmul_rn(w2,v1y)),
                       __fmul_rn(w3,v2y));
        rz = pz;
        ra = 1.0f;
      }
    }
  }
  out[pid] = make_float4(rx, ry, rz, ra);
}

extern "C" void kernel_launch(void* const* d_in, const int* in_sizes, int n_in,
                              void* d_out, int out_size, void* d_ws, size_t ws_size,
                              hipStream_t stream) {
  const float* tris = (const float*)d_in[0];
  float4* out = (float4*)d_out;
  hipLaunchKernelGGL(render_kernel, dim3((TSIZE * TSIZE) / 256), dim3(256), 0, stream,
                     tris, out);
}

// Round 3
// 149.485 us; speedup vs baseline: 1.0725x; 1.0725x over previous
//
#include <hip/hip_runtime.h>

#define TSIZE 512
#define NT 512
#define EPSV 1e-9f

// ---------------- two-pass version: setup precomputes per-tri records in d_ws,
// main loops with triangle data in SGPRs (uniform s_load), no LDS. -------------
//
// record (16 floats / 64 B per tri):
//  0: v1x  1: v1y  2: (v0y-v1y)  3: (v0x-v1x)     -> pAB
//  4: v2x  5: v2y  6: (v1y-v2y)  7: (v1x-v2x)     -> pCB
//  8: v0x  9: v0y 10: (v2y-v0y) 11: (v2x-v0x)     -> pCA
// 12: rw=1/ws 13: v2z 14: (v0z-v2z) 15: (v1z-v2z)
// bnds[t] = { xmn|xmx<<16, ymn|ymx<<16 }
// Edge-function chain stays bit-exact vs numpy (__f*_rn, same order, coeffs are
// the same single-rounded subs). Interp/z use rw + FMA refactor: value-only
// deviations (~1ulp); z-test flips at ties are value-continuous -> harmless.

__global__ void render_setup(const float* __restrict__ tris,
                             float* __restrict__ recs,
                             uint2* __restrict__ bnds,
                             float* __restrict__ zminp) {
  __shared__ float sred[8];
  const int t = threadIdx.x;  // 512 threads, 1 block
  const float* tp = tris + t * 9;
  float v0x = tp[0], v0y = tp[1], v0z = tp[2];
  float v1x = tp[3], v1y = tp[4], v1z = tp[5];
  float v2x = tp[6], v2y = tp[7], v2z = tp[8];

  float w = __fsub_rn(__fmul_rn(__fsub_rn(v1x, v0x), __fsub_rn(v2y, v0y)),
                      __fmul_rn(__fsub_rn(v1y, v0y), __fsub_rn(v2x, v0x)));
  bool valid = (w >= EPSV);
  float ws = valid ? w : 1.0f;

  float* r = recs + (t << 4);
  r[0] = v1x;  r[1] = v1y;  r[2]  = __fsub_rn(v0y, v1y); r[3]  = __fsub_rn(v0x, v1x);
  r[4] = v2x;  r[5] = v2y;  r[6]  = __fsub_rn(v1y, v2y); r[7]  = __fsub_rn(v1x, v2x);
  r[8] = v0x;  r[9] = v0y;  r[10] = __fsub_rn(v2y, v0y); r[11] = __fsub_rn(v2x, v0x);
  r[12] = __fdiv_rn(1.0f, ws);
  r[13] = v2z;
  r[14] = __fsub_rn(v0z, v2z);
  r[15] = __fsub_rn(v1z, v2z);

  int xmn = 0, xmx = 0, ymn = 0, ymx = 0;
  if (valid) {
    float bxn = fminf(v0x, fminf(v1x, v2x));
    float byn = fminf(v0y, fminf(v1y, v2y));
    float bxx = fmaxf(v0x, fmaxf(v1x, v2x));
    float byx = fmaxf(v0y, fmaxf(v1y, v2y));
    xmn = (int)floorf(__fmul_rn(__fadd_rn(fminf(fmaxf(bxn, -1.0f), 1.0f), 1.0f), 256.0f));
    ymn = (int)floorf(__fmul_rn(__fadd_rn(fminf(fmaxf(byn, -1.0f), 1.0f), 1.0f), 256.0f));
    xmx = (int)floorf(__fmul_rn(__fadd_rn(fminf(fmaxf(bxx, -1.0f), 1.0f), 1.0f), 256.0f));
    ymx = (int)floorf(__fmul_rn(__fadd_rn(fminf(fmaxf(byx, -1.0f), 1.0f), 1.0f), 256.0f));
  }
  bnds[t] = make_uint2((unsigned)xmn | ((unsigned)xmx << 16),
                       (unsigned)ymn | ((unsigned)ymx << 16));

  // zmin over all vertex z (exact, order-independent)
  float zm = fminf(v0z, fminf(v1z, v2z));
  for (int off = 32; off > 0; off >>= 1) zm = fminf(zm, __shfl_down(zm, off, 64));
  if ((t & 63) == 0) sred[t >> 6] = zm;
  __syncthreads();
  if (t == 0) {
    float z = sred[0];
    for (int k = 1; k < 8; ++k) z = fminf(z, sred[k]);
    zminp[0] = z;
  }
}

__global__ __launch_bounds__(256) void render_main(const float* __restrict__ recs,
                                                   const uint2* __restrict__ bnds,
                                                   const float* __restrict__ zminp,
                                                   float4* __restrict__ out) {
  const int tid = threadIdx.x;
  const int bb = blockIdx.x;
  const int i = bb >> 1;                       // provably uniform (SGPR)
  const int j = ((bb & 1) << 8) | tid;
  const float delta = 2.0f / 511.0f;
  const float px = __fadd_rn(-1.0f, __fmul_rn((float)i, delta));
  const float py = __fadd_rn(-1.0f, __fmul_rn((float)j, delta));
  const unsigned jw0 = (unsigned)(j & ~63);    // wave-uniform strip base

  float zb = zminp[0];
  float rx = 0.0f, ry = 0.0f, ra = 0.0f;

  for (int t = 0; t < NT; ++t) {
    uint2 bw = bnds[t];
    unsigned xm = bw.x & 0xFFFFu, xM = bw.x >> 16;
    if ((unsigned)i < xm || (unsigned)i >= xM) continue;       // uniform skip
    unsigned ym = bw.y & 0xFFFFu, yM = bw.y >> 16;
    if (ym >= jw0 + 64u || yM <= jw0) continue;                // wave-uniform skip

    const float* r = recs + (t << 4);
    float pAB = __fsub_rn(__fmul_rn(__fsub_rn(px, r[0]), r[2]),
                          __fmul_rn(__fsub_rn(py, r[1]), r[3]));
    float pCB = __fsub_rn(__fmul_rn(__fsub_rn(px, r[4]), r[6]),
                          __fmul_rn(__fsub_rn(py, r[5]), r[7]));
    float pCA = __fsub_rn(__fmul_rn(__fsub_rn(px, r[8]), r[10]),
                          __fmul_rn(__fsub_rn(py, r[9]), r[11]));
    bool ins = (pAB > 0.0f) & (pCB > 0.0f) & (pCA > 0.0f) &
               ((unsigned)j >= ym) & ((unsigned)j < yM);
    if (__any(ins)) {
      float rw = r[12];
      float w1 = __fmul_rn(pCB, rw);
      float w2 = __fmul_rn(pCA, rw);
      float pz = __fmaf_rn(w1, r[14], __fmaf_rn(w2, r[15], r[13]));
      bool m = ins & (pz >= zb);
      float nrx = __fmaf_rn(w1, -r[11], __fmaf_rn(w2, r[7], r[4]));
      float nry = __fmaf_rn(w1, -r[10], __fmaf_rn(w2, r[6], r[5]));
      zb = m ? pz : zb;
      rx = m ? nrx : rx;
      ry = m ? nry : ry;
      ra = m ? 1.0f : ra;
    }
  }
  float rz = (ra != 0.0f) ? zb : 0.0f;
  out[(i << 9) | j] = make_float4(rx, ry, rz, ra);
}

// ---------------- fallback (round-2 kernel, passes): used if ws too small ----
__global__ __launch_bounds__(256) void render_fallback(const float* __restrict__ tris,
                                                       float4* __restrict__ out) {
  __shared__ float sf[10 * NT];
  __shared__ unsigned short sb[4 * NT];
  __shared__ float s_zred[4];
  const int tid = threadIdx.x;
  for (int t = tid; t < NT; t += 256) {
    const float* tp = tris + t * 9;
    float v0x = tp[0], v0y = tp[1], v0z = tp[2];
    float v1x = tp[3], v1y = tp[4], v1z = tp[5];
    float v2x = tp[6], v2y = tp[7], v2z = tp[8];
    sf[0*NT+t] = v0x; sf[1*NT+t] = v0y; sf[2*NT+t] = v0z;
    sf[3*NT+t] = v1x; sf[4*NT+t] = v1y; sf[5*NT+t] = v1z;
    sf[6*NT+t] = v2x; sf[7*NT+t] = v2y; sf[8*NT+t] = v2z;
    float w = __fsub_rn(__fmul_rn(__fsub_rn(v1x,v0x), __fsub_rn(v2y,v0y)),
                        __fmul_rn(__fsub_rn(v1y,v0y), __fsub_rn(v2x,v0x)));
    bool valid = (w >= EPSV);
    sf[9*NT+t] = valid ? w : 1.0f;
    int xmn = 0, xmx = 0, ymn = 0, ymx = 0;
    if (valid) {
      float bxn = fminf(v0x, fminf(v1x, v2x));
      float byn = fminf(v0y, fminf(v1y, v2y));
      float bxx = fmaxf(v0x, fmaxf(v1x, v2x));
      float byx = fmaxf(v0y, fmaxf(v1y, v2y));
      xmn = (int)floorf(__fmul_rn(__fadd_rn(fminf(fmaxf(bxn,-1.0f),1.0f),1.0f),256.0f));
      ymn = (int)floorf(__fmul_rn(__fadd_rn(fminf(fmaxf(byn,-1.0f),1.0f),1.0f),256.0f));
      xmx = (int)floorf(__fmul_rn(__fadd_rn(fminf(fmaxf(bxx,-1.0f),1.0f),1.0f),256.0f));
      ymx = (int)floorf(__fmul_rn(__fadd_rn(fminf(fmaxf(byx,-1.0f),1.0f),1.0f),256.0f));
    }
    sb[0*NT+t] = (unsigned short)xmn; sb[1*NT+t] = (unsigned short)xmx;
    sb[2*NT+t] = (unsigned short)ymn; sb[3*NT+t] = (unsigned short)ymx;
  }
  float zm = 3.4e38f;
  for (int v = tid; v < NT * 3; v += 256) zm = fminf(zm, tris[v * 3 + 2]);
  for (int off = 32; off > 0; off >>= 1) zm = fminf(zm, __shfl_down(zm, off, 64));
  if ((tid & 63) == 0) s_zred[tid >> 6] = zm;
  __syncthreads();
  zm = fminf(fminf(s_zred[0], s_zred[1]), fminf(s_zred[2], s_zred[3]));
  const int pid = blockIdx.x * 256 + tid;
  const int i = pid >> 9;
  const int j = pid & (TSIZE - 1);
  const float delta = 2.0f / 511.0f;
  const float px = __fadd_rn(-1.0f, __fmul_rn((float)i, delta));
  const float py = __fadd_rn(-1.0f, __fmul_rn((float)j, delta));
  float zb = zm, rx = 0.0f, ry = 0.0f, rz = 0.0f, ra = 0.0f;
  for (int t = 0; t < NT; ++t) {
    int xmn = sb[0*NT+t], xmx = sb[1*NT+t];
    int ymn = sb[2*NT+t], ymx = sb[3*NT+t];
    if (i < xmn || i >= xmx || j < ymn || j >= ymx) continue;
    float v0x = sf[0*NT+t], v0y = sf[1*NT+t];
    float v1x = sf[3*NT+t], v1y = sf[4*NT+t];
    float v2x = sf[6*NT+t], v2y = sf[7*NT+t];
    float pAB = __fsub_rn(__fmul_rn(__fsub_rn(px,v1x), __fsub_rn(v0y,v1y)),
                          __fmul_rn(__fsub_rn(py,v1y), __fsub_rn(v0x,v1x)));
    float pCB = __fsub_rn(__fmul_rn(__fsub_rn(px,v2x), __fsub_rn(v1y,v2y)),
                          __fmul_rn(__fsub_rn(py,v2y), __fsub_rn(v1x,v2x)));
    float pCA = __fsub_rn(__fmul_rn(__fsub_rn(px,v0x), __fsub_rn(v2y,v0y)),
                          __fmul_rn(__fsub_rn(py,v0y), __fsub_rn(v2x,v0x)));
    float prod = __fmul_rn(__fmul_rn(fmaxf(pAB,0.0f), fmaxf(pCB,0.0f)), fmaxf(pCA,0.0f));
    if (prod > 0.0f) {
      float ws = sf[9*NT+t];
      float w1 = __fdiv_rn(pCB, ws);
      float w2 = __fdiv_rn(pCA, ws);
      float w3 = __fsub_rn(__fsub_rn(1.0f, w1), w2);
      float v0z = sf[2*NT+t], v1z = sf[5*NT+t], v2z = sf[8*NT+t];
      float pz = __fadd_rn(__fadd_rn(__fmul_rn(w1,v0z), __fmul_rn(w2,v1z)),
                           __fmul_rn(w3,v2z));
      if (pz >= zb) {
        zb = pz;
        rx = __fadd_rn(__fadd_rn(__fmul_rn(w1,v0x), __fmul_rn(w2,v1x)),
                       __fmul_rn(w3,v2x));
        ry = __fadd_rn(__fadd_rn(__fmul_rn(w1,v0y), __fmul_rn(w2,v1y)),
                       __fmul_rn(w3,v2y));
        rz = pz; ra = 1.0f;
      }
    }
  }
  out[pid] = make_float4(rx, ry, rz, ra);
}

extern "C" void kernel_launch(void* const* d_in, const int* in_sizes, int n_in,
                              void* d_out, int out_size, void* d_ws, size_t ws_size,
                              hipStream_t stream) {
  const float* tris = (const float*)d_in[0];
  float4* out = (float4*)d_out;
  const size_t REC_B = (size_t)NT * 64;        // 32768
  const size_t BND_B = (size_t)NT * 8;         // 4096
  const size_t NEED = REC_B + BND_B + 16;
  if (ws_size >= NEED) {
    float* recs = (float*)d_ws;
    uint2* bnds = (uint2*)((char*)d_ws + REC_B);
    float* zminp = (float*)((char*)d_ws + REC_B + BND_B);
    hipLaunchKernelGGL(render_setup, dim3(1), dim3(NT), 0, stream, tris, recs, bnds, zminp);
    hipLaunchKernelGGL(render_main, dim3((TSIZE * TSIZE) / 256), dim3(256), 0, stream,
                       recs, bnds, zminp, out);
  } else {
    hipLaunchKernelGGL(render_fallback, dim3((TSIZE * TSIZE) / 256), dim3(256), 0, stream,
                       tris, out);
  }
}

// Round 4
// 142.198 us; speedup vs baseline: 1.1275x; 1.0512x over previous
//
#include <hip/hip_runtime.h>

#define TSIZE 512
#define NT 512
#define EPSV 1e-9f

// Two-pass: setup precomputes per-tri records + packed bounds in d_ws;
// main stages them into LDS (in-order ds_read pipeline, broadcast reads)
// and runs the lean per-pixel loop (no divides, FMA interp).
//
// record (16 floats / 64 B per tri):
//  0: v1x  1: v1y  2: (v0y-v1y)  3: (v0x-v1x)     -> pAB
//  4: v2x  5: v2y  6: (v1y-v2y)  7: (v1x-v2x)     -> pCB
//  8: v0x  9: v0y 10: (v2y-v0y) 11: (v2x-v0x)     -> pCA
// 12: rw=1/ws 13: v2z 14: (v0z-v2z) 15: (v1z-v2z)
// bnds[t] = { xmn|xmx<<16, ymn|ymx<<16 }
// Edge-function chain is bit-exact vs numpy (__f*_rn, same order; coeffs are
// the same single-rounded subs). Interp/z-test deviations are value-only.

__global__ void render_setup(const float* __restrict__ tris,
                             float* __restrict__ recs,
                             uint2* __restrict__ bnds,
                             float* __restrict__ zminp) {
  __shared__ float sred[8];
  const int t = threadIdx.x;  // 512 threads, 1 block
  const float* tp = tris + t * 9;
  float v0x = tp[0], v0y = tp[1], v0z = tp[2];
  float v1x = tp[3], v1y = tp[4], v1z = tp[5];
  float v2x = tp[6], v2y = tp[7], v2z = tp[8];

  float w = __fsub_rn(__fmul_rn(__fsub_rn(v1x, v0x), __fsub_rn(v2y, v0y)),
                      __fmul_rn(__fsub_rn(v1y, v0y), __fsub_rn(v2x, v0x)));
  bool valid = (w >= EPSV);
  float ws = valid ? w : 1.0f;

  float* r = recs + (t << 4);
  r[0] = v1x;  r[1] = v1y;  r[2]  = __fsub_rn(v0y, v1y); r[3]  = __fsub_rn(v0x, v1x);
  r[4] = v2x;  r[5] = v2y;  r[6]  = __fsub_rn(v1y, v2y); r[7]  = __fsub_rn(v1x, v2x);
  r[8] = v0x;  r[9] = v0y;  r[10] = __fsub_rn(v2y, v0y); r[11] = __fsub_rn(v2x, v0x);
  r[12] = __fdiv_rn(1.0f, ws);
  r[13] = v2z;
  r[14] = __fsub_rn(v0z, v2z);
  r[15] = __fsub_rn(v1z, v2z);

  int xmn = 0, xmx = 0, ymn = 0, ymx = 0;
  if (valid) {
    float bxn = fminf(v0x, fminf(v1x, v2x));
    float byn = fminf(v0y, fminf(v1y, v2y));
    float bxx = fmaxf(v0x, fmaxf(v1x, v2x));
    float byx = fmaxf(v0y, fmaxf(v1y, v2y));
    xmn = (int)floorf(__fmul_rn(__fadd_rn(fminf(fmaxf(bxn, -1.0f), 1.0f), 1.0f), 256.0f));
    ymn = (int)floorf(__fmul_rn(__fadd_rn(fminf(fmaxf(byn, -1.0f), 1.0f), 1.0f), 256.0f));
    xmx = (int)floorf(__fmul_rn(__fadd_rn(fminf(fmaxf(bxx, -1.0f), 1.0f), 1.0f), 256.0f));
    ymx = (int)floorf(__fmul_rn(__fadd_rn(fminf(fmaxf(byx, -1.0f), 1.0f), 1.0f), 256.0f));
  }
  bnds[t] = make_uint2((unsigned)xmn | ((unsigned)xmx << 16),
                       (unsigned)ymn | ((unsigned)ymx << 16));

  float zm = fminf(v0z, fminf(v1z, v2z));
  for (int off = 32; off > 0; off >>= 1) zm = fminf(zm, __shfl_down(zm, off, 64));
  if ((t & 63) == 0) sred[t >> 6] = zm;
  __syncthreads();
  if (t == 0) {
    float z = sred[0];
    for (int k = 1; k < 8; ++k) z = fminf(z, sred[k]);
    zminp[0] = z;
  }
}

__global__ __launch_bounds__(256) void render_main(const float* __restrict__ recs,
                                                   const uint2* __restrict__ bnds,
                                                   const float* __restrict__ zminp,
                                                   float4* __restrict__ out) {
  __shared__ float lrec[NT * 16];   // 32 KB
  __shared__ uint2 lbnd[NT];        // 4 KB

  const int tid = threadIdx.x;

  // stage records (2048 float4) + bounds (512 uint2) into LDS
  {
    const float4* g4 = (const float4*)recs;
    float4* l4 = (float4*)lrec;
#pragma unroll
    for (int k = 0; k < 8; ++k) l4[tid + 256 * k] = g4[tid + 256 * k];
    lbnd[tid] = bnds[tid];
    lbnd[tid + 256] = bnds[tid + 256];
  }
  const float zm0 = zminp[0];
  __syncthreads();

  const int bb = blockIdx.x;
  const int i = bb >> 1;                     // block-uniform
  const int j = ((bb & 1) << 8) | tid;
  const float delta = 2.0f / 511.0f;
  const float px = __fadd_rn(-1.0f, __fmul_rn((float)i, delta));
  const float py = __fadd_rn(-1.0f, __fmul_rn((float)j, delta));
  const unsigned jw0 = (unsigned)(j & ~63);  // wave-uniform strip base

  float zb = zm0;
  float rx = 0.0f, ry = 0.0f, ra = 0.0f;

  uint2 bwn = lbnd[0];                       // software-pipelined bounds read
  for (int t = 0; t < NT; ++t) {
    uint2 bw = bwn;
    bwn = lbnd[(t + 1) & (NT - 1)];
    unsigned xm = bw.x & 0xFFFFu, xM = bw.x >> 16;
    if ((unsigned)i < xm || (unsigned)i >= xM) continue;       // uniform skip
    unsigned ym = bw.y & 0xFFFFu, yM = bw.y >> 16;
    if (ym >= jw0 + 64u || yM <= jw0) continue;                // wave-uniform skip

    const float* r = &lrec[t << 4];
    float pAB = __fsub_rn(__fmul_rn(__fsub_rn(px, r[0]), r[2]),
                          __fmul_rn(__fsub_rn(py, r[1]), r[3]));
    float pCB = __fsub_rn(__fmul_rn(__fsub_rn(px, r[4]), r[6]),
                          __fmul_rn(__fsub_rn(py, r[5]), r[7]));
    float pCA = __fsub_rn(__fmul_rn(__fsub_rn(px, r[8]), r[10]),
                          __fmul_rn(__fsub_rn(py, r[9]), r[11]));
    bool ins = (pAB > 0.0f) & (pCB > 0.0f) & (pCA > 0.0f) &
               ((unsigned)j >= ym) & ((unsigned)j < yM);
    if (__any(ins)) {
      float rw = r[12];
      float w1 = __fmul_rn(pCB, rw);
      float w2 = __fmul_rn(pCA, rw);
      float pz = __fmaf_rn(w1, r[14], __fmaf_rn(w2, r[15], r[13]));
      bool m = ins & (pz >= zb);
      float nrx = __fmaf_rn(w1, -r[11], __fmaf_rn(w2, r[7], r[4]));
      float nry = __fmaf_rn(w1, -r[10], __fmaf_rn(w2, r[6], r[5]));
      zb = m ? pz : zb;
      rx = m ? nrx : rx;
      ry = m ? nry : ry;
      ra = m ? 1.0f : ra;
    }
  }
  float rz = (ra != 0.0f) ? zb : 0.0f;
  out[(i << 9) | j] = make_float4(rx, ry, rz, ra);
}

// ---------------- fallback (round-2 kernel, passes): used if ws too small ----
__global__ __launch_bounds__(256) void render_fallback(const float* __restrict__ tris,
                                                       float4* __restrict__ out) {
  __shared__ float sf[10 * NT];
  __shared__ unsigned short sb[4 * NT];
  __shared__ float s_zred[4];
  const int tid = threadIdx.x;
  for (int t = tid; t < NT; t += 256) {
    const float* tp = tris + t * 9;
    float v0x = tp[0], v0y = tp[1], v0z = tp[2];
    float v1x = tp[3], v1y = tp[4], v1z = tp[5];
    float v2x = tp[6], v2y = tp[7], v2z = tp[8];
    sf[0*NT+t] = v0x; sf[1*NT+t] = v0y; sf[2*NT+t] = v0z;
    sf[3*NT+t] = v1x; sf[4*NT+t] = v1y; sf[5*NT+t] = v1z;
    sf[6*NT+t] = v2x; sf[7*NT+t] = v2y; sf[8*NT+t] = v2z;
    float w = __fsub_rn(__fmul_rn(__fsub_rn(v1x,v0x), __fsub_rn(v2y,v0y)),
                        __fmul_rn(__fsub_rn(v1y,v0y), __fsub_rn(v2x,v0x)));
    bool valid = (w >= EPSV);
    sf[9*NT+t] = valid ? w : 1.0f;
    int xmn = 0, xmx = 0, ymn = 0, ymx = 0;
    if (valid) {
      float bxn = fminf(v0x, fminf(v1x, v2x));
      float byn = fminf(v0y, fminf(v1y, v2y));
      float bxx = fmaxf(v0x, fmaxf(v1x, v2x));
      float byx = fmaxf(v0y, fmaxf(v1y, v2y));
      xmn = (int)floorf(__fmul_rn(__fadd_rn(fminf(fmaxf(bxn,-1.0f),1.0f),1.0f),256.0f));
      ymn = (int)floorf(__fmul_rn(__fadd_rn(fminf(fmaxf(byn,-1.0f),1.0f),1.0f),256.0f));
      xmx = (int)floorf(__fmul_rn(__fadd_rn(fminf(fmaxf(bxx,-1.0f),1.0f),1.0f),256.0f));
      ymx = (int)floorf(__fmul_rn(__fadd_rn(fminf(fmaxf(byx,-1.0f),1.0f),1.0f),256.0f));
    }
    sb[0*NT+t] = (unsigned short)xmn; sb[1*NT+t] = (unsigned short)xmx;
    sb[2*NT+t] = (unsigned short)ymn; sb[3*NT+t] = (unsigned short)ymx;
  }
  float zm = 3.4e38f;
  for (int v = tid; v < NT * 3; v += 256) zm = fminf(zm, tris[v * 3 + 2]);
  for (int off = 32; off > 0; off >>= 1) zm = fminf(zm, __shfl_down(zm, off, 64));
  if ((tid & 63) == 0) s_zred[tid >> 6] = zm;
  __syncthreads();
  zm = fminf(fminf(s_zred[0], s_zred[1]), fminf(s_zred[2], s_zred[3]));
  const int pid = blockIdx.x * 256 + tid;
  const int i = pid >> 9;
  const int j = pid & (TSIZE - 1);
  const float delta = 2.0f / 511.0f;
  const float px = __fadd_rn(-1.0f, __fmul_rn((float)i, delta));
  const float py = __fadd_rn(-1.0f, __fmul_rn((float)j, delta));
  float zb = zm, rx = 0.0f, ry = 0.0f, rz = 0.0f, ra = 0.0f;
  for (int t = 0; t < NT; ++t) {
    int xmn = sb[0*NT+t], xmx = sb[1*NT+t];
    int ymn = sb[2*NT+t], ymx = sb[3*NT+t];
    if (i < xmn || i >= xmx || j < ymn || j >= ymx) continue;
    float v0x = sf[0*NT+t], v0y = sf[1*NT+t];
    float v1x = sf[3*NT+t], v1y = sf[4*NT+t];
    float v2x = sf[6*NT+t], v2y = sf[7*NT+t];
    float pAB = __fsub_rn(__fmul_rn(__fsub_rn(px,v1x), __fsub_rn(v0y,v1y)),
                          __fmul_rn(__fsub_rn(py,v1y), __fsub_rn(v0x,v1x)));
    float pCB = __fsub_rn(__fmul_rn(__fsub_rn(px,v2x), __fsub_rn(v1y,v2y)),
                          __fmul_rn(__fsub_rn(py,v2y), __fsub_rn(v1x,v2x)));
    float pCA = __fsub_rn(__fmul_rn(__fsub_rn(px,v0x), __fsub_rn(v2y,v0y)),
                          __fmul_rn(__fsub_rn(py,v0y), __fsub_rn(v2x,v0x)));
    float prod = __fmul_rn(__fmul_rn(fmaxf(pAB,0.0f), fmaxf(pCB,0.0f)), fmaxf(pCA,0.0f));
    if (prod > 0.0f) {
      float ws = sf[9*NT+t];
      float w1 = __fdiv_rn(pCB, ws);
      float w2 = __fdiv_rn(pCA, ws);
      float w3 = __fsub_rn(__fsub_rn(1.0f, w1), w2);
      float v0z = sf[2*NT+t], v1z = sf[5*NT+t], v2z = sf[8*NT+t];
      float pz = __fadd_rn(__fadd_rn(__fmul_rn(w1,v0z), __fmul_rn(w2,v1z)),
                           __fmul_rn(w3,v2z));
      if (pz >= zb) {
        zb = pz;
        rx = __fadd_rn(__fadd_rn(__fmul_rn(w1,v0x), __fmul_rn(w2,v1x)),
                       __fmul_rn(w3,v2x));
        ry = __fadd_rn(__fadd_rn(__fmul_rn(w1,v0y), __fmul_rn(w2,v1y)),
                       __fmul_rn(w3,v2y));
        rz = pz; ra = 1.0f;
      }
    }
  }
  out[pid] = make_float4(rx, ry, rz, ra);
}

extern "C" void kernel_launch(void* const* d_in, const int* in_sizes, int n_in,
                              void* d_out, int out_size, void* d_ws, size_t ws_size,
                              hipStream_t stream) {
  const float* tris = (const float*)d_in[0];
  float4* out = (float4*)d_out;
  const size_t REC_B = (size_t)NT * 64;        // 32768
  const size_t BND_B = (size_t)NT * 8;         // 4096
  const size_t NEED = REC_B + BND_B + 16;
  if (ws_size >= NEED) {
    float* recs = (float*)d_ws;
    uint2* bnds = (uint2*)((char*)d_ws + REC_B);
    float* zminp = (float*)((char*)d_ws + REC_B + BND_B);
    hipLaunchKernelGGL(render_setup, dim3(1), dim3(NT), 0, stream, tris, recs, bnds, zminp);
    hipLaunchKernelGGL(render_main, dim3((TSIZE * TSIZE) / 256), dim3(256), 0, stream,
                       recs, bnds, zminp, out);
  } else {
    hipLaunchKernelGGL(render_fallback, dim3((TSIZE * TSIZE) / 256), dim3(256), 0, stream,
                       tris, out);
  }
}

// Round 5
// 104.478 us; speedup vs baseline: 1.5345x; 1.3610x over previous
//
#include <hip/hip_runtime.h>

#define TSIZE 512
#define NT 512
#define EPSV 1e-9f

// Pass 1: per-tri records + packed AABB. Pass 2: per-(row,64j-strip) 512-bit
// survivor masks. Pass 3: per-pixel loop visits only surviving tris (uniform
// ctz loop over SGPR mask), eval from LDS broadcasts.
//
// record (16 floats / 64 B per tri):
//  0: v1x  1: v1y  2: (v0y-v1y)  3: (v0x-v1x)     -> pAB
//  4: v2x  5: v2y  6: (v1y-v2y)  7: (v1x-v2x)     -> pCB
//  8: v0x  9: v0y 10: (v2y-v0y) 11: (v2x-v0x)     -> pCA
// 12: rw=1/ws 13: v2z 14: (v0z-v2z) 15: (v1z-v2z)
// bnds[t] = { xmn|xmx<<16, ymn|ymx<<16 }
// Edge-function chain bit-exact vs numpy; interp/z deviations value-only.

__global__ void render_setup(const float* __restrict__ tris,
                             float* __restrict__ recs,
                             uint2* __restrict__ bnds,
                             float* __restrict__ zminp) {
  __shared__ float sred[8];
  const int t = threadIdx.x;  // 512 threads, 1 block
  const float* tp = tris + t * 9;
  float v0x = tp[0], v0y = tp[1], v0z = tp[2];
  float v1x = tp[3], v1y = tp[4], v1z = tp[5];
  float v2x = tp[6], v2y = tp[7], v2z = tp[8];

  float w = __fsub_rn(__fmul_rn(__fsub_rn(v1x, v0x), __fsub_rn(v2y, v0y)),
                      __fmul_rn(__fsub_rn(v1y, v0y), __fsub_rn(v2x, v0x)));
  bool valid = (w >= EPSV);
  float ws = valid ? w : 1.0f;

  float* r = recs + (t << 4);
  r[0] = v1x;  r[1] = v1y;  r[2]  = __fsub_rn(v0y, v1y); r[3]  = __fsub_rn(v0x, v1x);
  r[4] = v2x;  r[5] = v2y;  r[6]  = __fsub_rn(v1y, v2y); r[7]  = __fsub_rn(v1x, v2x);
  r[8] = v0x;  r[9] = v0y;  r[10] = __fsub_rn(v2y, v0y); r[11] = __fsub_rn(v2x, v0x);
  r[12] = __fdiv_rn(1.0f, ws);
  r[13] = v2z;
  r[14] = __fsub_rn(v0z, v2z);
  r[15] = __fsub_rn(v1z, v2z);

  int xmn = 0, xmx = 0, ymn = 0, ymx = 0;
  if (valid) {
    float bxn = fminf(v0x, fminf(v1x, v2x));
    float byn = fminf(v0y, fminf(v1y, v2y));
    float bxx = fmaxf(v0x, fmaxf(v1x, v2x));
    float byx = fmaxf(v0y, fmaxf(v1y, v2y));
    xmn = (int)floorf(__fmul_rn(__fadd_rn(fminf(fmaxf(bxn, -1.0f), 1.0f), 1.0f), 256.0f));
    ymn = (int)floorf(__fmul_rn(__fadd_rn(fminf(fmaxf(byn, -1.0f), 1.0f), 1.0f), 256.0f));
    xmx = (int)floorf(__fmul_rn(__fadd_rn(fminf(fmaxf(bxx, -1.0f), 1.0f), 1.0f), 256.0f));
    ymx = (int)floorf(__fmul_rn(__fadd_rn(fminf(fmaxf(byx, -1.0f), 1.0f), 1.0f), 256.0f));
  }
  bnds[t] = make_uint2((unsigned)xmn | ((unsigned)xmx << 16),
                       (unsigned)ymn | ((unsigned)ymx << 16));

  float zm = fminf(v0z, fminf(v1z, v2z));
  for (int off = 32; off > 0; off >>= 1) zm = fminf(zm, __shfl_down(zm, off, 64));
  if ((t & 63) == 0) sred[t >> 6] = zm;
  __syncthreads();
  if (t == 0) {
    float z = sred[0];
    for (int k = 1; k < 8; ++k) z = fminf(z, sred[k]);
    zminp[0] = z;
  }
}

// Pass 2: masks[(i*8 + jstrip)*8 + w] — bit b of word w set iff tri t=w*64+b
// has i in [xm,xM) and [jw0,jw0+64) intersecting [ym,yM).
__global__ __launch_bounds__(256) void render_masks(const uint2* __restrict__ bnds,
                                                    unsigned long long* __restrict__ masks) {
  __shared__ uint2 sb[NT];
  const int tid = threadIdx.x;
  sb[tid] = bnds[tid];
  sb[tid + 256] = bnds[tid + 256];
  __syncthreads();
  const int s = blockIdx.x * 256 + tid;      // strip id 0..4095
  const unsigned i = (unsigned)(s >> 3);
  const unsigned jw0 = (unsigned)((s & 7) << 6);
#pragma unroll 1
  for (int w = 0; w < 8; ++w) {
    unsigned long long m = 0;
#pragma unroll 8
    for (int b = 0; b < 64; ++b) {
      uint2 bw = sb[(w << 6) + b];
      unsigned xm = bw.x & 0xFFFFu, xM = bw.x >> 16;
      unsigned ym = bw.y & 0xFFFFu, yM = bw.y >> 16;
      bool pass = (i >= xm) & (i < xM) & (ym < jw0 + 64u) & (yM > jw0);
      m |= ((unsigned long long)pass) << b;
    }
    masks[(size_t)s * 8 + w] = m;
  }
}

__global__ __launch_bounds__(256) void render_main(const float* __restrict__ recs,
                                                   const uint2* __restrict__ bnds,
                                                   const unsigned long long* __restrict__ masks,
                                                   const float* __restrict__ zminp,
                                                   float4* __restrict__ out) {
  __shared__ float lrec[NT * 16];     // 32 KB
  __shared__ unsigned lbY[NT];        // 2 KB: ym|yM<<16

  const int tid = threadIdx.x;
  {
    const float4* g4 = (const float4*)recs;
    float4* l4 = (float4*)lrec;
#pragma unroll
    for (int k = 0; k < 8; ++k) l4[tid + 256 * k] = g4[tid + 256 * k];
    lbY[tid] = bnds[tid].y;
    lbY[tid + 256] = bnds[tid + 256].y;
  }
  const float zm0 = zminp[0];
  __syncthreads();

  const int bb = blockIdx.x;
  const int i = bb >> 1;                       // block-uniform
  const int j = ((bb & 1) << 8) | tid;
  const float delta = 2.0f / 511.0f;
  const float px = __fadd_rn(-1.0f, __fmul_rn((float)i, delta));
  const float py = __fadd_rn(-1.0f, __fmul_rn((float)j, delta));

  // wave-uniform strip id -> scalar mask load (one wait, amortized)
  const int jstrip = __builtin_amdgcn_readfirstlane(tid >> 6);
  const size_t sid = (size_t)(i << 3) + ((bb & 1) << 2) + jstrip;
  const unsigned long long* mp = masks + sid * 8;

  float zb = zm0;
  float rx = 0.0f, ry = 0.0f, ra = 0.0f;

#pragma unroll 1
  for (int w = 0; w < 8; ++w) {
    unsigned long long m = mp[w];
    while (m) {
      const int b = __builtin_ctzll(m);
      m &= m - 1;
      const int t = (w << 6) + b;

      const float* r = &lrec[t << 4];
      const unsigned yb = lbY[t];
      const unsigned ym = yb & 0xFFFFu, yM = yb >> 16;

      float pAB = __fsub_rn(__fmul_rn(__fsub_rn(px, r[0]), r[2]),
                            __fmul_rn(__fsub_rn(py, r[1]), r[3]));
      float pCB = __fsub_rn(__fmul_rn(__fsub_rn(px, r[4]), r[6]),
                            __fmul_rn(__fsub_rn(py, r[5]), r[7]));
      float pCA = __fsub_rn(__fmul_rn(__fsub_rn(px, r[8]), r[10]),
                            __fmul_rn(__fsub_rn(py, r[9]), r[11]));
      bool ins = (pAB > 0.0f) & (pCB > 0.0f) & (pCA > 0.0f) &
                 ((unsigned)j >= ym) & ((unsigned)j < yM);
      if (__any(ins)) {
        float rw = r[12];
        float w1 = __fmul_rn(pCB, rw);
        float w2 = __fmul_rn(pCA, rw);
        float pz = __fmaf_rn(w1, r[14], __fmaf_rn(w2, r[15], r[13]));
        bool mk = ins & (pz >= zb);
        float nrx = __fmaf_rn(w1, -r[11], __fmaf_rn(w2, r[7], r[4]));
        float nry = __fmaf_rn(w1, -r[10], __fmaf_rn(w2, r[6], r[5]));
        zb = mk ? pz : zb;
        rx = mk ? nrx : rx;
        ry = mk ? nry : ry;
        ra = mk ? 1.0f : ra;
      }
    }
  }
  float rz = (ra != 0.0f) ? zb : 0.0f;
  out[(i << 9) | j] = make_float4(rx, ry, rz, ra);
}

// ---- mid fallback: round-4 main (no masks; needs 36 KB ws) ----
__global__ __launch_bounds__(256) void render_main_nomask(const float* __restrict__ recs,
                                                          const uint2* __restrict__ bnds,
                                                          const float* __restrict__ zminp,
                                                          float4* __restrict__ out) {
  __shared__ float lrec[NT * 16];
  __shared__ uint2 lbnd[NT];
  const int tid = threadIdx.x;
  {
    const float4* g4 = (const float4*)recs;
    float4* l4 = (float4*)lrec;
#pragma unroll
    for (int k = 0; k < 8; ++k) l4[tid + 256 * k] = g4[tid + 256 * k];
    lbnd[tid] = bnds[tid];
    lbnd[tid + 256] = bnds[tid + 256];
  }
  const float zm0 = zminp[0];
  __syncthreads();
  const int bb = blockIdx.x;
  const int i = bb >> 1;
  const int j = ((bb & 1) << 8) | tid;
  const float delta = 2.0f / 511.0f;
  const float px = __fadd_rn(-1.0f, __fmul_rn((float)i, delta));
  const float py = __fadd_rn(-1.0f, __fmul_rn((float)j, delta));
  const unsigned jw0 = (unsigned)(j & ~63);
  float zb = zm0, rx = 0.0f, ry = 0.0f, ra = 0.0f;
  uint2 bwn = lbnd[0];
  for (int t = 0; t < NT; ++t) {
    uint2 bw = bwn;
    bwn = lbnd[(t + 1) & (NT - 1)];
    unsigned xm = bw.x & 0xFFFFu, xM = bw.x >> 16;
    if ((unsigned)i < xm || (unsigned)i >= xM) continue;
    unsigned ym = bw.y & 0xFFFFu, yM = bw.y >> 16;
    if (ym >= jw0 + 64u || yM <= jw0) continue;
    const float* r = &lrec[t << 4];
    float pAB = __fsub_rn(__fmul_rn(__fsub_rn(px, r[0]), r[2]),
                          __fmul_rn(__fsub_rn(py, r[1]), r[3]));
    float pCB = __fsub_rn(__fmul_rn(__fsub_rn(px, r[4]), r[6]),
                          __fmul_rn(__fsub_rn(py, r[5]), r[7]));
    float pCA = __fsub_rn(__fmul_rn(__fsub_rn(px, r[8]), r[10]),
                          __fmul_rn(__fsub_rn(py, r[9]), r[11]));
    bool ins = (pAB > 0.0f) & (pCB > 0.0f) & (pCA > 0.0f) &
               ((unsigned)j >= ym) & ((unsigned)j < yM);
    if (__any(ins)) {
      float rw = r[12];
      float w1 = __fmul_rn(pCB, rw);
      float w2 = __fmul_rn(pCA, rw);
      float pz = __fmaf_rn(w1, r[14], __fmaf_rn(w2, r[15], r[13]));
      bool mk = ins & (pz >= zb);
      float nrx = __fmaf_rn(w1, -r[11], __fmaf_rn(w2, r[7], r[4]));
      float nry = __fmaf_rn(w1, -r[10], __fmaf_rn(w2, r[6], r[5]));
      zb = mk ? pz : zb;
      rx = mk ? nrx : rx;
      ry = mk ? nry : ry;
      ra = mk ? 1.0f : ra;
    }
  }
  float rz = (ra != 0.0f) ? zb : 0.0f;
  out[(i << 9) | j] = make_float4(rx, ry, rz, ra);
}

// ---- last-resort fallback (round-2 single kernel, no ws) ----
__global__ __launch_bounds__(256) void render_fallback(const float* __restrict__ tris,
                                                       float4* __restrict__ out) {
  __shared__ float sf[10 * NT];
  __shared__ unsigned short sb[4 * NT];
  __shared__ float s_zred[4];
  const int tid = threadIdx.x;
  for (int t = tid; t < NT; t += 256) {
    const float* tp = tris + t * 9;
    float v0x = tp[0], v0y = tp[1], v0z = tp[2];
    float v1x = tp[3], v1y = tp[4], v1z = tp[5];
    float v2x = tp[6], v2y = tp[7], v2z = tp[8];
    sf[0*NT+t] = v0x; sf[1*NT+t] = v0y; sf[2*NT+t] = v0z;
    sf[3*NT+t] = v1x; sf[4*NT+t] = v1y; sf[5*NT+t] = v1z;
    sf[6*NT+t] = v2x; sf[7*NT+t] = v2y; sf[8*NT+t] = v2z;
    float w = __fsub_rn(__fmul_rn(__fsub_rn(v1x,v0x), __fsub_rn(v2y,v0y)),
                        __fmul_rn(__fsub_rn(v1y,v0y), __fsub_rn(v2x,v0x)));
    bool valid = (w >= EPSV);
    sf[9*NT+t] = valid ? w : 1.0f;
    int xmn = 0, xmx = 0, ymn = 0, ymx = 0;
    if (valid) {
      float bxn = fminf(v0x, fminf(v1x, v2x));
      float byn = fminf(v0y, fminf(v1y, v2y));
      float bxx = fmaxf(v0x, fmaxf(v1x, v2x));
      float byx = fmaxf(v0y, fmaxf(v1y, v2y));
      xmn = (int)floorf(__fmul_rn(__fadd_rn(fminf(fmaxf(bxn,-1.0f),1.0f),1.0f),256.0f));
      ymn = (int)floorf(__fmul_rn(__fadd_rn(fminf(fmaxf(byn,-1.0f),1.0f),1.0f),256.0f));
      xmx = (int)floorf(__fmul_rn(__fadd_rn(fminf(fmaxf(bxx,-1.0f),1.0f),1.0f),256.0f));
      ymx = (int)floorf(__fmul_rn(__fadd_rn(fminf(fmaxf(byx,-1.0f),1.0f),1.0f),256.0f));
    }
    sb[0*NT+t] = (unsigned short)xmn; sb[1*NT+t] = (unsigned short)xmx;
    sb[2*NT+t] = (unsigned short)ymn; sb[3*NT+t] = (unsigned short)ymx;
  }
  float zm = 3.4e38f;
  for (int v = tid; v < NT * 3; v += 256) zm = fminf(zm, tris[v * 3 + 2]);
  for (int off = 32; off > 0; off >>= 1) zm = fminf(zm, __shfl_down(zm, off, 64));
  if ((tid & 63) == 0) s_zred[tid >> 6] = zm;
  __syncthreads();
  zm = fminf(fminf(s_zred[0], s_zred[1]), fminf(s_zred[2], s_zred[3]));
  const int pid = blockIdx.x * 256 + tid;
  const int i = pid >> 9;
  const int j = pid & (TSIZE - 1);
  const float delta = 2.0f / 511.0f;
  const float px = __fadd_rn(-1.0f, __fmul_rn((float)i, delta));
  const float py = __fadd_rn(-1.0f, __fmul_rn((float)j, delta));
  float zb = zm, rx = 0.0f, ry = 0.0f, rz = 0.0f, ra = 0.0f;
  for (int t = 0; t < NT; ++t) {
    int xmn = sb[0*NT+t], xmx = sb[1*NT+t];
    int ymn = sb[2*NT+t], ymx = sb[3*NT+t];
    if (i < xmn || i >= xmx || j < ymn || j >= ymx) continue;
    float v0x = sf[0*NT+t], v0y = sf[1*NT+t];
    float v1x = sf[3*NT+t], v1y = sf[4*NT+t];
    float v2x = sf[6*NT+t], v2y = sf[7*NT+t];
    float pAB = __fsub_rn(__fmul_rn(__fsub_rn(px,v1x), __fsub_rn(v0y,v1y)),
                          __fmul_rn(__fsub_rn(py,v1y), __fsub_rn(v0x,v1x)));
    float pCB = __fsub_rn(__fmul_rn(__fsub_rn(px,v2x), __fsub_rn(v1y,v2y)),
                          __fmul_rn(__fsub_rn(py,v2y), __fsub_rn(v1x,v2x)));
    float pCA = __fsub_rn(__fmul_rn(__fsub_rn(px,v0x), __fsub_rn(v2y,v0y)),
                          __fmul_rn(__fsub_rn(py,v0y), __fsub_rn(v2x,v0x)));
    float prod = __fmul_rn(__fmul_rn(fmaxf(pAB,0.0f), fmaxf(pCB,0.0f)), fmaxf(pCA,0.0f));
    if (prod > 0.0f) {
      float ws = sf[9*NT+t];
      float w1 = __fdiv_rn(pCB, ws);
      float w2 = __fdiv_rn(pCA, ws);
      float w3 = __fsub_rn(__fsub_rn(1.0f, w1), w2);
      float v0z = sf[2*NT+t], v1z = sf[5*NT+t], v2z = sf[8*NT+t];
      float pz = __fadd_rn(__fadd_rn(__fmul_rn(w1,v0z), __fmul_rn(w2,v1z)),
                           __fmul_rn(w3,v2z));
      if (pz >= zb) {
        zb = pz;
        rx = __fadd_rn(__fadd_rn(__fmul_rn(w1,v0x), __fmul_rn(w2,v1x)),
                       __fmul_rn(w3,v2x));
        ry = __fadd_rn(__fadd_rn(__fmul_rn(w1,v0y), __fmul_rn(w2,v1y)),
                       __fmul_rn(w3,v2y));
        rz = pz; ra = 1.0f;
      }
    }
  }
  out[pid] = make_float4(rx, ry, rz, ra);
}

extern "C" void kernel_launch(void* const* d_in, const int* in_sizes, int n_in,
                              void* d_out, int out_size, void* d_ws, size_t ws_size,
                              hipStream_t stream) {
  const float* tris = (const float*)d_in[0];
  float4* out = (float4*)d_out;
  const size_t REC_B = (size_t)NT * 64;          // 32768
  const size_t BND_B = (size_t)NT * 8;           // 4096
  const size_t ZMIN_B = 16;
  const size_t MASK_B = (size_t)4096 * 8 * 8;    // 262144
  const size_t NEED_SMALL = REC_B + BND_B + ZMIN_B;
  const size_t NEED_FULL = NEED_SMALL + MASK_B;

  float* recs = (float*)d_ws;
  uint2* bnds = (uint2*)((char*)d_ws + REC_B);
  float* zminp = (float*)((char*)d_ws + REC_B + BND_B);
  unsigned long long* masks = (unsigned long long*)((char*)d_ws + NEED_SMALL);

  if (ws_size >= NEED_FULL) {
    hipLaunchKernelGGL(render_setup, dim3(1), dim3(NT), 0, stream, tris, recs, bnds, zminp);
    hipLaunchKernelGGL(render_masks, dim3(16), dim3(256), 0, stream, bnds, masks);
    hipLaunchKernelGGL(render_main, dim3((TSIZE * TSIZE) / 256), dim3(256), 0, stream,
                       recs, bnds, masks, zminp, out);
  } else if (ws_size >= NEED_SMALL) {
    hipLaunchKernelGGL(render_setup, dim3(1), dim3(NT), 0, stream, tris, recs, bnds, zminp);
    hipLaunchKernelGGL(render_main_nomask, dim3((TSIZE * TSIZE) / 256), dim3(256), 0, stream,
                       recs, bnds, zminp, out);
  } else {
    hipLaunchKernelGGL(render_fallback, dim3((TSIZE * TSIZE) / 256), dim3(256), 0, stream,
                       tris, out);
  }
}

// Round 6
// 94.499 us; speedup vs baseline: 1.6966x; 1.1056x over previous
//
#include <hip/hip_runtime.h>

#define TSIZE 512
#define NT 512
#define EPSV 1e-9f

// Pass 1 (setup): per-tri records, packed AABB, per-edge (A,S,K) for the slice
//   test, zmin.
// Pass 2 (masks): per-(row i, 64j-strip) 512-bit survivor mask, refined by the
//   exact y-interval of the triangle slice at x=px_i (conservative margins).
// Pass 3 (main): per-pixel loop over survivors only (uniform ctz loop over
//   scalar mask), 2-deep software-pipelined LDS record fetch.
//
// record (16 floats / 64 B per tri):
//  0: v1x  1: v1y  2: (v0y-v1y)  3: (v0x-v1x)     -> pAB
//  4: v2x  5: v2y  6: (v1y-v2y)  7: (v1x-v2x)     -> pCB
//  8: v0x  9: v0y 10: (v2y-v0y) 11: (v2x-v0x)     -> pCA
// 12: rw=1/ws 13: v2z 14: (v0z-v2z) 15: (v1z-v2z)
// kas (12 floats / 48 B per tri): {A,S,K} per edge, p_e = K + A*px + S*py
// bnds[t] = { xmn|xmx<<16, ymn|ymx<<16 }
// Edge-function chain in main is bit-exact vs numpy; mask math is conservative.

__global__ void render_setup(const float* __restrict__ tris,
                             float* __restrict__ recs,
                             uint2* __restrict__ bnds,
                             float* __restrict__ kas,
                             float* __restrict__ zminp) {
  __shared__ float sred[8];
  const int t = threadIdx.x;  // 512 threads, 1 block
  const float* tp = tris + t * 9;
  float v0x = tp[0], v0y = tp[1], v0z = tp[2];
  float v1x = tp[3], v1y = tp[4], v1z = tp[5];
  float v2x = tp[6], v2y = tp[7], v2z = tp[8];

  float w = __fsub_rn(__fmul_rn(__fsub_rn(v1x, v0x), __fsub_rn(v2y, v0y)),
                      __fmul_rn(__fsub_rn(v1y, v0y), __fsub_rn(v2x, v0x)));
  bool valid = (w >= EPSV);
  float ws = valid ? w : 1.0f;

  float r2  = __fsub_rn(v0y, v1y), r3  = __fsub_rn(v0x, v1x);
  float r6  = __fsub_rn(v1y, v2y), r7  = __fsub_rn(v1x, v2x);
  float r10 = __fsub_rn(v2y, v0y), r11 = __fsub_rn(v2x, v0x);

  float* r = recs + (t << 4);
  r[0] = v1x;  r[1] = v1y;  r[2]  = r2;  r[3]  = r3;
  r[4] = v2x;  r[5] = v2y;  r[6]  = r6;  r[7]  = r7;
  r[8] = v0x;  r[9] = v0y;  r[10] = r10; r[11] = r11;
  r[12] = __fdiv_rn(1.0f, ws);
  r[13] = v2z;
  r[14] = __fsub_rn(v0z, v2z);
  r[15] = __fsub_rn(v1z, v2z);

  // slice-test coefficients (conservative use only)
  float* ka = kas + t * 12;
  ka[0]  = r2;   ka[1]  = -r3;   ka[2]  = v1y * r3 - v1x * r2;
  ka[3]  = r6;   ka[4]  = -r7;   ka[5]  = v2y * r7 - v2x * r6;
  ka[6]  = r10;  ka[7]  = -r11;  ka[8]  = v0y * r11 - v0x * r10;
  ka[9] = 0.0f; ka[10] = 0.0f; ka[11] = 0.0f;

  int xmn = 0, xmx = 0, ymn = 0, ymx = 0;
  if (valid) {
    float bxn = fminf(v0x, fminf(v1x, v2x));
    float byn = fminf(v0y, fminf(v1y, v2y));
    float bxx = fmaxf(v0x, fmaxf(v1x, v2x));
    float byx = fmaxf(v0y, fmaxf(v1y, v2y));
    xmn = (int)floorf(__fmul_rn(__fadd_rn(fminf(fmaxf(bxn, -1.0f), 1.0f), 1.0f), 256.0f));
    ymn = (int)floorf(__fmul_rn(__fadd_rn(fminf(fmaxf(byn, -1.0f), 1.0f), 1.0f), 256.0f));
    xmx = (int)floorf(__fmul_rn(__fadd_rn(fminf(fmaxf(bxx, -1.0f), 1.0f), 1.0f), 256.0f));
    ymx = (int)floorf(__fmul_rn(__fadd_rn(fminf(fmaxf(byx, -1.0f), 1.0f), 1.0f), 256.0f));
  }
  bnds[t] = make_uint2((unsigned)xmn | ((unsigned)xmx << 16),
                       (unsigned)ymn | ((unsigned)ymx << 16));

  float zm = fminf(v0z, fminf(v1z, v2z));
  for (int off = 32; off > 0; off >>= 1) zm = fminf(zm, __shfl_down(zm, off, 64));
  if ((t & 63) == 0) sred[t >> 6] = zm;
  __syncthreads();
  if (t == 0) {
    float z = sred[0];
    for (int k = 1; k < 8; ++k) z = fminf(z, sred[k]);
    zminp[0] = z;
  }
}

// Pass 2: 128 blocks x 256 threads; thread handles (strip s, word w) with
// s = blockIdx*32 + (tid&31), w = tid>>5  -> lanes 0..31 share w,b => LDS
// broadcasts. Bit b of word w: tri t=w*64+b survives (box-x, box-y-strip,
// slice-y-strip with margin).
__global__ __launch_bounds__(256) void render_masks(const uint2* __restrict__ bnds,
                                                    const float* __restrict__ kas,
                                                    unsigned long long* __restrict__ masks) {
  __shared__ uint2 sbn[NT];
  __shared__ float ska[NT * 12];
  const int tid = threadIdx.x;
  sbn[tid] = bnds[tid];
  sbn[tid + 256] = bnds[tid + 256];
  {
    const float4* g4 = (const float4*)kas;
    float4* l4 = (float4*)ska;
#pragma unroll
    for (int k = 0; k < 6; ++k) l4[tid + 256 * k] = g4[tid + 256 * k];
  }
  __syncthreads();

  const int s = blockIdx.x * 32 + (tid & 31);   // strip 0..4095
  const int w = tid >> 5;                        // word 0..7
  const int i = s >> 3;
  const unsigned jw0 = (unsigned)((s & 7) << 6);
  const float delta = 2.0f / 511.0f;
  const float px = -1.0f + (float)i * delta;
  const float pyL = -1.0f + (float)jw0 * delta;
  const float pyR = -1.0f + (float)(jw0 + 63u) * delta;

  unsigned long long m = 0;
#pragma unroll 4
  for (int b = 0; b < 64; ++b) {
    const int t = (w << 6) + b;
    uint2 bw = sbn[t];
    unsigned xm = bw.x & 0xFFFFu, xM = bw.x >> 16;
    unsigned ym = bw.y & 0xFFFFu, yM = bw.y >> 16;
    bool pass = ((unsigned)i >= xm) & ((unsigned)i < xM) &
                (ym < jw0 + 64u) & (yM > jw0);
    if (pass) {
      const float4* ka4 = (const float4*)&ska[t * 12];
      float4 e01 = ka4[0];   // A0 S0 K0 A1
      float4 e12 = ka4[1];   // S1 K1 A2 S2
      float4 e2k = ka4[2];   // K2 pad pad pad
      float ylo = -1e30f, yhi = 1e30f;
      {
        float S = e01.y, c = e01.z + e01.x * px;
        if (S > 1e-20f)       { float cd = -c / S; ylo = fmaxf(ylo, cd - (0.005f + 4e-6f * fabsf(cd))); }
        else if (S < -1e-20f) { float cd = -c / S; yhi = fminf(yhi, cd + (0.005f + 4e-6f * fabsf(cd))); }
      }
      {
        float S = e12.x, c = e12.y + e01.w * px;
        if (S > 1e-20f)       { float cd = -c / S; ylo = fmaxf(ylo, cd - (0.005f + 4e-6f * fabsf(cd))); }
        else if (S < -1e-20f) { float cd = -c / S; yhi = fminf(yhi, cd + (0.005f + 4e-6f * fabsf(cd))); }
      }
      {
        float S = e12.w, c = e2k.x + e12.z * px;
        if (S > 1e-20f)       { float cd = -c / S; ylo = fmaxf(ylo, cd - (0.005f + 4e-6f * fabsf(cd))); }
        else if (S < -1e-20f) { float cd = -c / S; yhi = fminf(yhi, cd + (0.005f + 4e-6f * fabsf(cd))); }
      }
      pass = (ylo <= pyR) & (yhi >= pyL);
    }
    m |= ((unsigned long long)(pass ? 1 : 0)) << b;
  }
  masks[(size_t)s * 8 + w] = m;
}

__global__ __launch_bounds__(256) void render_main(const float* __restrict__ recs,
                                                   const uint2* __restrict__ bnds,
                                                   const unsigned long long* __restrict__ masks,
                                                   const float* __restrict__ zminp,
                                                   float4* __restrict__ out) {
  __shared__ float lrec[NT * 16];     // 32 KB
  __shared__ unsigned lbY[NT];        // 2 KB: ym|yM<<16

  const int tid = threadIdx.x;
  {
    const float4* g4 = (const float4*)recs;
    float4* l4 = (float4*)lrec;
#pragma unroll
    for (int k = 0; k < 8; ++k) l4[tid + 256 * k] = g4[tid + 256 * k];
    lbY[tid] = bnds[tid].y;
    lbY[tid + 256] = bnds[tid + 256].y;
  }
  const float zm0 = zminp[0];
  __syncthreads();

  const int bb = blockIdx.x;
  const int i = bb >> 1;                       // block-uniform
  const int j = ((bb & 1) << 8) | tid;
  const float delta = 2.0f / 511.0f;
  const float px = __fadd_rn(-1.0f, __fmul_rn((float)i, delta));
  const float py = __fadd_rn(-1.0f, __fmul_rn((float)j, delta));

  const int jstrip = __builtin_amdgcn_readfirstlane(tid >> 6);
  const size_t sid = (size_t)(i << 3) + ((bb & 1) << 2) + jstrip;
  const unsigned long long* mp = masks + sid * 8;

  float zb = zm0;
  float rx = 0.0f, ry = 0.0f, ra = 0.0f;
  const float4* lr4 = (const float4*)lrec;

#pragma unroll 1
  for (int w = 0; w < 8; ++w) {
    unsigned long long m = mp[w];
    if (!m) continue;
    int b = __builtin_ctzll(m);
    m &= m - 1;
    int t = (w << 6) + b;
    float4 c0 = lr4[t * 4 + 0], c1 = lr4[t * 4 + 1];
    float4 c2 = lr4[t * 4 + 2], c3 = lr4[t * 4 + 3];
    unsigned cyb = lbY[t];
    while (1) {
      // prefetch next survivor while evaluating current
      int tn = -1;
      float4 n0, n1, n2, n3;
      unsigned nyb = 0;
      if (m) {
        int bn = __builtin_ctzll(m);
        m &= m - 1;
        tn = (w << 6) + bn;
        n0 = lr4[tn * 4 + 0]; n1 = lr4[tn * 4 + 1];
        n2 = lr4[tn * 4 + 2]; n3 = lr4[tn * 4 + 3];
        nyb = lbY[tn];
      }

      const unsigned ym = cyb & 0xFFFFu, yM = cyb >> 16;
      float pAB = __fsub_rn(__fmul_rn(__fsub_rn(px, c0.x), c0.z),
                            __fmul_rn(__fsub_rn(py, c0.y), c0.w));
      float pCB = __fsub_rn(__fmul_rn(__fsub_rn(px, c1.x), c1.z),
                            __fmul_rn(__fsub_rn(py, c1.y), c1.w));
      float pCA = __fsub_rn(__fmul_rn(__fsub_rn(px, c2.x), c2.z),
                            __fmul_rn(__fsub_rn(py, c2.y), c2.w));
      bool ins = (pAB > 0.0f) & (pCB > 0.0f) & (pCA > 0.0f) &
                 ((unsigned)j >= ym) & ((unsigned)j < yM);
      if (__any(ins)) {
        float rw = c3.x;
        float w1 = __fmul_rn(pCB, rw);
        float w2 = __fmul_rn(pCA, rw);
        float pz = __fmaf_rn(w1, c3.z, __fmaf_rn(w2, c3.w, c3.y));
        bool mk = ins & (pz >= zb);
        float nrx = __fmaf_rn(w1, -c2.w, __fmaf_rn(w2, c1.w, c1.x));
        float nry = __fmaf_rn(w1, -c2.z, __fmaf_rn(w2, c1.z, c1.y));
        zb = mk ? pz : zb;
        rx = mk ? nrx : rx;
        ry = mk ? nry : ry;
        ra = mk ? 1.0f : ra;
      }

      if (tn < 0) break;
      c0 = n0; c1 = n1; c2 = n2; c3 = n3; cyb = nyb;
    }
  }
  float rz = (ra != 0.0f) ? zb : 0.0f;
  out[(i << 9) | j] = make_float4(rx, ry, rz, ra);
}

// ---- last-resort fallback (round-2 single kernel, no ws) ----
__global__ __launch_bounds__(256) void render_fallback(const float* __restrict__ tris,
                                                       float4* __restrict__ out) {
  __shared__ float sf[10 * NT];
  __shared__ unsigned short sb[4 * NT];
  __shared__ float s_zred[4];
  const int tid = threadIdx.x;
  for (int t = tid; t < NT; t += 256) {
    const float* tp = tris + t * 9;
    float v0x = tp[0], v0y = tp[1], v0z = tp[2];
    float v1x = tp[3], v1y = tp[4], v1z = tp[5];
    float v2x = tp[6], v2y = tp[7], v2z = tp[8];
    sf[0*NT+t] = v0x; sf[1*NT+t] = v0y; sf[2*NT+t] = v0z;
    sf[3*NT+t] = v1x; sf[4*NT+t] = v1y; sf[5*NT+t] = v1z;
    sf[6*NT+t] = v2x; sf[7*NT+t] = v2y; sf[8*NT+t] = v2z;
    float w = __fsub_rn(__fmul_rn(__fsub_rn(v1x,v0x), __fsub_rn(v2y,v0y)),
                        __fmul_rn(__fsub_rn(v1y,v0y), __fsub_rn(v2x,v0x)));
    bool valid = (w >= EPSV);
    sf[9*NT+t] = valid ? w : 1.0f;
    int xmn = 0, xmx = 0, ymn = 0, ymx = 0;
    if (valid) {
      float bxn = fminf(v0x, fminf(v1x, v2x));
      float byn = fminf(v0y, fminf(v1y, v2y));
      float bxx = fmaxf(v0x, fmaxf(v1x, v2x));
      float byx = fmaxf(v0y, fmaxf(v1y, v2y));
      xmn = (int)floorf(__fmul_rn(__fadd_rn(fminf(fmaxf(bxn,-1.0f),1.0f),1.0f),256.0f));
      ymn = (int)floorf(__fmul_rn(__fadd_rn(fminf(fmaxf(byn,-1.0f),1.0f),1.0f),256.0f));
      xmx = (int)floorf(__fmul_rn(__fadd_rn(fminf(fmaxf(bxx,-1.0f),1.0f),1.0f),256.0f));
      ymx = (int)floorf(__fmul_rn(__fadd_rn(fminf(fmaxf(byx,-1.0f),1.0f),1.0f),256.0f));
    }
    sb[0*NT+t] = (unsigned short)xmn; sb[1*NT+t] = (unsigned short)xmx;
    sb[2*NT+t] = (unsigned short)ymn; sb[3*NT+t] = (unsigned short)ymx;
  }
  float zm = 3.4e38f;
  for (int v = tid; v < NT * 3; v += 256) zm = fminf(zm, tris[v * 3 + 2]);
  for (int off = 32; off > 0; off >>= 1) zm = fminf(zm, __shfl_down(zm, off, 64));
  if ((tid & 63) == 0) s_zred[tid >> 6] = zm;
  __syncthreads();
  zm = fminf(fminf(s_zred[0], s_zred[1]), fminf(s_zred[2], s_zred[3]));
  const int pid = blockIdx.x * 256 + tid;
  const int i = pid >> 9;
  const int j = pid & (TSIZE - 1);
  const float delta = 2.0f / 511.0f;
  const float px = __fadd_rn(-1.0f, __fmul_rn((float)i, delta));
  const float py = __fadd_rn(-1.0f, __fmul_rn((float)j, delta));
  float zb = zm, rx = 0.0f, ry = 0.0f, rz = 0.0f, ra = 0.0f;
  for (int t = 0; t < NT; ++t) {
    int xmn = sb[0*NT+t], xmx = sb[1*NT+t];
    int ymn = sb[2*NT+t], ymx = sb[3*NT+t];
    if (i < xmn || i >= xmx || j < ymn || j >= ymx) continue;
    float v0x = sf[0*NT+t], v0y = sf[1*NT+t];
    float v1x = sf[3*NT+t], v1y = sf[4*NT+t];
    float v2x = sf[6*NT+t], v2y = sf[7*NT+t];
    float pAB = __fsub_rn(__fmul_rn(__fsub_rn(px,v1x), __fsub_rn(v0y,v1y)),
                          __fmul_rn(__fsub_rn(py,v1y), __fsub_rn(v0x,v1x)));
    float pCB = __fsub_rn(__fmul_rn(__fsub_rn(px,v2x), __fsub_rn(v1y,v2y)),
                          __fmul_rn(__fsub_rn(py,v2y), __fsub_rn(v1x,v2x)));
    float pCA = __fsub_rn(__fmul_rn(__fsub_rn(px,v0x), __fsub_rn(v2y,v0y)),
                          __fmul_rn(__fsub_rn(py,v0y), __fsub_rn(v2x,v0x)));
    float prod = __fmul_rn(__fmul_rn(fmaxf(pAB,0.0f), fmaxf(pCB,0.0f)), fmaxf(pCA,0.0f));
    if (prod > 0.0f) {
      float ws = sf[9*NT+t];
      float w1 = __fdiv_rn(pCB, ws);
      float w2 = __fdiv_rn(pCA, ws);
      float w3 = __fsub_rn(__fsub_rn(1.0f, w1), w2);
      float v0z = sf[2*NT+t], v1z = sf[5*NT+t], v2z = sf[8*NT+t];
      float pz = __fadd_rn(__fadd_rn(__fmul_rn(w1,v0z), __fmul_rn(w2,v1z)),
                           __fmul_rn(w3,v2z));
      if (pz >= zb) {
        zb = pz;
        rx = __fadd_rn(__fadd_rn(__fmul_rn(w1,v0x), __fmul_rn(w2,v1x)),
                       __fmul_rn(w3,v2x));
        ry = __fadd_rn(__fadd_rn(__fmul_rn(w1,v0y), __fmul_rn(w2,v1y)),
                       __fmul_rn(w3,v2y));
        rz = pz; ra = 1.0f;
      }
    }
  }
  out[pid] = make_float4(rx, ry, rz, ra);
}

extern "C" void kernel_launch(void* const* d_in, const int* in_sizes, int n_in,
                              void* d_out, int out_size, void* d_ws, size_t ws_size,
                              hipStream_t stream) {
  const float* tris = (const float*)d_in[0];
  float4* out = (float4*)d_out;
  const size_t REC_B  = (size_t)NT * 64;          // 32768
  const size_t BND_B  = (size_t)NT * 8;           // 4096
  const size_t ZMIN_B = 64;
  const size_t KAS_B  = (size_t)NT * 48;          // 24576
  const size_t MASK_B = (size_t)4096 * 8 * 8;     // 262144
  const size_t NEED_FULL = REC_B + BND_B + ZMIN_B + KAS_B + MASK_B;

  float* recs  = (float*)d_ws;
  uint2* bnds  = (uint2*)((char*)d_ws + REC_B);
  float* zminp = (float*)((char*)d_ws + REC_B + BND_B);
  float* kas   = (float*)((char*)d_ws + REC_B + BND_B + ZMIN_B);
  unsigned long long* masks =
      (unsigned long long*)((char*)d_ws + REC_B + BND_B + ZMIN_B + KAS_B);

  if (ws_size >= NEED_FULL) {
    hipLaunchKernelGGL(render_setup, dim3(1), dim3(NT), 0, stream,
                       tris, recs, bnds, kas, zminp);
    hipLaunchKernelGGL(render_masks, dim3(128), dim3(256), 0, stream,
                       bnds, kas, masks);
    hipLaunchKernelGGL(render_main, dim3((TSIZE * TSIZE) / 256), dim3(256), 0, stream,
                       recs, bnds, masks, zminp, out);
  } else {
    hipLaunchKernelGGL(render_fallback, dim3((TSIZE * TSIZE) / 256), dim3(256), 0, stream,
                       tris, out);
  }
}

// Round 7
// 94.417 us; speedup vs baseline: 1.6980x; 1.0009x over previous
//
#include <hip/hip_runtime.h>

#define TSIZE 512
#define NT 512
#define EPSV 1e-9f
#define NPIX (TSIZE * TSIZE)

// Painter loop == lexicographic argmax over (pz, t) (running-max acceptance).
// Pass 1 (setup): per-tri records, packed AABB, slice-test coeffs, zmin.
// Pass 2 (masks): per-(row, 64j-strip) 512-bit survivor mask (AABB + exact
//   row-slice y-interval with conservative margin).
// Pass 3 (partial x2 chunks of 256 tris): per-pixel (zmax, t_win) only.
// Pass 4 (merge): lex-merge chunks, one exact interpolation of the winner.
//
// record (16 floats / 64 B per tri):
//  0: v1x  1: v1y  2: (v0y-v1y)  3: (v0x-v1x)     -> pAB
//  4: v2x  5: v2y  6: (v1y-v2y)  7: (v1x-v2x)     -> pCB
//  8: v0x  9: v0y 10: (v2y-v0y) 11: (v2x-v0x)     -> pCA
// 12: rw=1/ws 13: v2z 14: (v0z-v2z) 15: (v1z-v2z)
// Edge/interp chains bit-exact vs numpy (__f*_rn, same order); mask math is
// conservative-only; chunk merge is exactly the reference's winner rule.

__global__ void render_setup(const float* __restrict__ tris,
                             float* __restrict__ recs,
                             uint2* __restrict__ bnds,
                             float* __restrict__ kas,
                             float* __restrict__ zminp) {
  __shared__ float sred[8];
  const int t = threadIdx.x;  // 512 threads, 1 block
  const float* tp = tris + t * 9;
  float v0x = tp[0], v0y = tp[1], v0z = tp[2];
  float v1x = tp[3], v1y = tp[4], v1z = tp[5];
  float v2x = tp[6], v2y = tp[7], v2z = tp[8];

  float w = __fsub_rn(__fmul_rn(__fsub_rn(v1x, v0x), __fsub_rn(v2y, v0y)),
                      __fmul_rn(__fsub_rn(v1y, v0y), __fsub_rn(v2x, v0x)));
  bool valid = (w >= EPSV);
  float ws = valid ? w : 1.0f;

  float r2  = __fsub_rn(v0y, v1y), r3  = __fsub_rn(v0x, v1x);
  float r6  = __fsub_rn(v1y, v2y), r7  = __fsub_rn(v1x, v2x);
  float r10 = __fsub_rn(v2y, v0y), r11 = __fsub_rn(v2x, v0x);

  float* r = recs + (t << 4);
  r[0] = v1x;  r[1] = v1y;  r[2]  = r2;  r[3]  = r3;
  r[4] = v2x;  r[5] = v2y;  r[6]  = r6;  r[7]  = r7;
  r[8] = v0x;  r[9] = v0y;  r[10] = r10; r[11] = r11;
  r[12] = __fdiv_rn(1.0f, ws);
  r[13] = v2z;
  r[14] = __fsub_rn(v0z, v2z);
  r[15] = __fsub_rn(v1z, v2z);

  float* ka = kas + t * 12;
  ka[0]  = r2;   ka[1]  = -r3;   ka[2]  = v1y * r3 - v1x * r2;
  ka[3]  = r6;   ka[4]  = -r7;   ka[5]  = v2y * r7 - v2x * r6;
  ka[6]  = r10;  ka[7]  = -r11;  ka[8]  = v0y * r11 - v0x * r10;
  ka[9] = 0.0f; ka[10] = 0.0f; ka[11] = 0.0f;

  int xmn = 0, xmx = 0, ymn = 0, ymx = 0;
  if (valid) {
    float bxn = fminf(v0x, fminf(v1x, v2x));
    float byn = fminf(v0y, fminf(v1y, v2y));
    float bxx = fmaxf(v0x, fmaxf(v1x, v2x));
    float byx = fmaxf(v0y, fmaxf(v1y, v2y));
    xmn = (int)floorf(__fmul_rn(__fadd_rn(fminf(fmaxf(bxn, -1.0f), 1.0f), 1.0f), 256.0f));
    ymn = (int)floorf(__fmul_rn(__fadd_rn(fminf(fmaxf(byn, -1.0f), 1.0f), 1.0f), 256.0f));
    xmx = (int)floorf(__fmul_rn(__fadd_rn(fminf(fmaxf(bxx, -1.0f), 1.0f), 1.0f), 256.0f));
    ymx = (int)floorf(__fmul_rn(__fadd_rn(fminf(fmaxf(byx, -1.0f), 1.0f), 1.0f), 256.0f));
  }
  bnds[t] = make_uint2((unsigned)xmn | ((unsigned)xmx << 16),
                       (unsigned)ymn | ((unsigned)ymx << 16));

  float zm = fminf(v0z, fminf(v1z, v2z));
  for (int off = 32; off > 0; off >>= 1) zm = fminf(zm, __shfl_down(zm, off, 64));
  if ((t & 63) == 0) sred[t >> 6] = zm;
  __syncthreads();
  if (t == 0) {
    float z = sred[0];
    for (int k = 1; k < 8; ++k) z = fminf(z, sred[k]);
    zminp[0] = z;
  }
}

__global__ __launch_bounds__(256) void render_masks(const uint2* __restrict__ bnds,
                                                    const float* __restrict__ kas,
                                                    unsigned long long* __restrict__ masks) {
  __shared__ uint2 sbn[NT];
  __shared__ float ska[NT * 12];
  const int tid = threadIdx.x;
  sbn[tid] = bnds[tid];
  sbn[tid + 256] = bnds[tid + 256];
  {
    const float4* g4 = (const float4*)kas;
    float4* l4 = (float4*)ska;
#pragma unroll
    for (int k = 0; k < 6; ++k) l4[tid + 256 * k] = g4[tid + 256 * k];
  }
  __syncthreads();

  const int s = blockIdx.x * 32 + (tid & 31);   // strip 0..4095
  const int w = tid >> 5;                        // word 0..7
  const int i = s >> 3;
  const unsigned jw0 = (unsigned)((s & 7) << 6);
  const float delta = 2.0f / 511.0f;
  const float px = -1.0f + (float)i * delta;
  const float pyL = -1.0f + (float)jw0 * delta;
  const float pyR = -1.0f + (float)(jw0 + 63u) * delta;

  unsigned long long m = 0;
#pragma unroll 4
  for (int b = 0; b < 64; ++b) {
    const int t = (w << 6) + b;
    uint2 bw = sbn[t];
    unsigned xm = bw.x & 0xFFFFu, xM = bw.x >> 16;
    unsigned ym = bw.y & 0xFFFFu, yM = bw.y >> 16;
    bool pass = ((unsigned)i >= xm) & ((unsigned)i < xM) &
                (ym < jw0 + 64u) & (yM > jw0);
    if (pass) {
      const float4* ka4 = (const float4*)&ska[t * 12];
      float4 e01 = ka4[0];
      float4 e12 = ka4[1];
      float4 e2k = ka4[2];
      float ylo = -1e30f, yhi = 1e30f;
      {
        float S = e01.y, c = e01.z + e01.x * px;
        if (S > 1e-20f)       { float cd = -c / S; ylo = fmaxf(ylo, cd - (0.005f + 4e-6f * fabsf(cd))); }
        else if (S < -1e-20f) { float cd = -c / S; yhi = fminf(yhi, cd + (0.005f + 4e-6f * fabsf(cd))); }
      }
      {
        float S = e12.x, c = e12.y + e01.w * px;
        if (S > 1e-20f)       { float cd = -c / S; ylo = fmaxf(ylo, cd - (0.005f + 4e-6f * fabsf(cd))); }
        else if (S < -1e-20f) { float cd = -c / S; yhi = fminf(yhi, cd + (0.005f + 4e-6f * fabsf(cd))); }
      }
      {
        float S = e12.w, c = e2k.x + e12.z * px;
        if (S > 1e-20f)       { float cd = -c / S; ylo = fmaxf(ylo, cd - (0.005f + 4e-6f * fabsf(cd))); }
        else if (S < -1e-20f) { float cd = -c / S; yhi = fminf(yhi, cd + (0.005f + 4e-6f * fabsf(cd))); }
      }
      pass = (ylo <= pyR) & (yhi >= pyL);
    }
    m |= ((unsigned long long)(pass ? 1 : 0)) << b;
  }
  masks[(size_t)s * 8 + w] = m;
}

// Pass 3: chunk = bid>>10 (256 tris), pixel-block = bid&1023.
// Tracks (zb, t_win) only; 17 KB LDS -> 8 blocks/CU -> 8 waves/SIMD.
__global__ __launch_bounds__(256) void render_partial(const float* __restrict__ recs,
                                                      const uint2* __restrict__ bnds,
                                                      const unsigned long long* __restrict__ masks,
                                                      const float* __restrict__ zminp,
                                                      float2* __restrict__ part) {
  __shared__ float4 lrec[256 * 4];    // 16 KB (chunk-local records)
  __shared__ unsigned lbY[256];       // 1 KB

  const int tid = threadIdx.x;
  const int bb = blockIdx.x;
  const int chunk = bb >> 10;          // 0 or 1
  const int pb = bb & 1023;
  const int tbase = chunk << 8;

  {
    const float4* g4 = (const float4*)recs + (tbase << 2);
#pragma unroll
    for (int k = 0; k < 4; ++k) lrec[tid + 256 * k] = g4[tid + 256 * k];
    lbY[tid] = bnds[tbase + tid].y;
  }
  const float zm0 = zminp[0];
  __syncthreads();

  const int i = pb >> 1;               // block-uniform
  const int j = ((pb & 1) << 8) | tid;
  const float delta = 2.0f / 511.0f;
  const float px = __fadd_rn(-1.0f, __fmul_rn((float)i, delta));
  const float py = __fadd_rn(-1.0f, __fmul_rn((float)j, delta));

  const int jstrip = __builtin_amdgcn_readfirstlane(tid >> 6);
  const size_t sid = (size_t)(i << 3) + ((pb & 1) << 2) + jstrip;
  const unsigned long long* mp = masks + sid * 8 + chunk * 4;
  unsigned long long mw0 = mp[0], mw1 = mp[1], mw2 = mp[2], mw3 = mp[3];

  float zb = zm0;
  int tw = -1;

#pragma unroll 1
  for (int w = 0; w < 4; ++w) {
    unsigned long long m = (w == 0) ? mw0 : (w == 1) ? mw1 : (w == 2) ? mw2 : mw3;
    if (!m) continue;
    int b = __builtin_ctzll(m);
    m &= m - 1;
    int t = (w << 6) + b;
    float4 c0 = lrec[t * 4 + 0], c1 = lrec[t * 4 + 1];
    float4 c2 = lrec[t * 4 + 2], c3 = lrec[t * 4 + 3];
    unsigned cyb = lbY[t];
    while (1) {
      // prefetch next survivor while evaluating current
      int tn = -1;
      float4 n0, n1, n2, n3;
      unsigned nyb = 0;
      if (m) {
        int bn = __builtin_ctzll(m);
        m &= m - 1;
        tn = (w << 6) + bn;
        n0 = lrec[tn * 4 + 0]; n1 = lrec[tn * 4 + 1];
        n2 = lrec[tn * 4 + 2]; n3 = lrec[tn * 4 + 3];
        nyb = lbY[tn];
      }

      const unsigned ym = cyb & 0xFFFFu, yM = cyb >> 16;
      float pAB = __fsub_rn(__fmul_rn(__fsub_rn(px, c0.x), c0.z),
                            __fmul_rn(__fsub_rn(py, c0.y), c0.w));
      float pCB = __fsub_rn(__fmul_rn(__fsub_rn(px, c1.x), c1.z),
                            __fmul_rn(__fsub_rn(py, c1.y), c1.w));
      float pCA = __fsub_rn(__fmul_rn(__fsub_rn(px, c2.x), c2.z),
                            __fmul_rn(__fsub_rn(py, c2.y), c2.w));
      bool ins = (pAB > 0.0f) & (pCB > 0.0f) & (pCA > 0.0f) &
                 ((unsigned)j >= ym) & ((unsigned)j < yM);
      if (__any(ins)) {
        float rw = c3.x;
        float w1 = __fmul_rn(pCB, rw);
        float w2 = __fmul_rn(pCA, rw);
        float pz = __fmaf_rn(w1, c3.z, __fmaf_rn(w2, c3.w, c3.y));
        bool mk = ins & (pz >= zb);
        zb = mk ? pz : zb;
        tw = mk ? (tbase + t) : tw;
      }

      if (tn < 0) break;
      c0 = n0; c1 = n1; c2 = n2; c3 = n3; cyb = nyb;
    }
  }
  part[(size_t)chunk * NPIX + (size_t)((i << 9) | j)] =
      make_float2(zb, __int_as_float(tw));
}

// Pass 4: lex-merge the two chunks, interpolate the winner once (exact chain).
__global__ __launch_bounds__(256) void render_merge(const float* __restrict__ recs,
                                                    const float2* __restrict__ part,
                                                    float4* __restrict__ out) {
  const int pid = blockIdx.x * 256 + threadIdx.x;
  float2 p0 = part[pid];
  float2 p1 = part[NPIX + pid];
  float z0 = p0.x; int t0 = __float_as_int(p0.y);
  float z1 = p1.x; int t1 = __float_as_int(p1.y);
  bool win1 = (z1 > z0) | ((z1 == z0) & (t1 > t0));
  int tw = win1 ? t1 : t0;
  float zf = win1 ? z1 : z0;

  float4 res = make_float4(0.0f, 0.0f, 0.0f, 0.0f);
  if (tw >= 0) {
    const int i = pid >> 9;
    const int j = pid & (TSIZE - 1);
    const float delta = 2.0f / 511.0f;
    const float px = __fadd_rn(-1.0f, __fmul_rn((float)i, delta));
    const float py = __fadd_rn(-1.0f, __fmul_rn((float)j, delta));
    const float4* r4 = (const float4*)(recs + ((size_t)tw << 4));
    float4 c1 = r4[1], c2 = r4[2], c3 = r4[3];
    float pCB = __fsub_rn(__fmul_rn(__fsub_rn(px, c1.x), c1.z),
                          __fmul_rn(__fsub_rn(py, c1.y), c1.w));
    float pCA = __fsub_rn(__fmul_rn(__fsub_rn(px, c2.x), c2.z),
                          __fmul_rn(__fsub_rn(py, c2.y), c2.w));
    float rw = c3.x;
    float w1 = __fmul_rn(pCB, rw);
    float w2 = __fmul_rn(pCA, rw);
    float rx = __fmaf_rn(w1, -c2.w, __fmaf_rn(w2, c1.w, c1.x));
    float ry = __fmaf_rn(w1, -c2.z, __fmaf_rn(w2, c1.z, c1.y));
    res = make_float4(rx, ry, zf, 1.0f);
  }
  out[pid] = res;
}

// ---- last-resort fallback (round-2 single kernel, no ws) ----
__global__ __launch_bounds__(256) void render_fallback(const float* __restrict__ tris,
                                                       float4* __restrict__ out) {
  __shared__ float sf[10 * NT];
  __shared__ unsigned short sb[4 * NT];
  __shared__ float s_zred[4];
  const int tid = threadIdx.x;
  for (int t = tid; t < NT; t += 256) {
    const float* tp = tris + t * 9;
    float v0x = tp[0], v0y = tp[1], v0z = tp[2];
    float v1x = tp[3], v1y = tp[4], v1z = tp[5];
    float v2x = tp[6], v2y = tp[7], v2z = tp[8];
    sf[0*NT+t] = v0x; sf[1*NT+t] = v0y; sf[2*NT+t] = v0z;
    sf[3*NT+t] = v1x; sf[4*NT+t] = v1y; sf[5*NT+t] = v1z;
    sf[6*NT+t] = v2x; sf[7*NT+t] = v2y; sf[8*NT+t] = v2z;
    float w = __fsub_rn(__fmul_rn(__fsub_rn(v1x,v0x), __fsub_rn(v2y,v0y)),
                        __fmul_rn(__fsub_rn(v1y,v0y), __fsub_rn(v2x,v0x)));
    bool valid = (w >= EPSV);
    sf[9*NT+t] = valid ? w : 1.0f;
    int xmn = 0, xmx = 0, ymn = 0, ymx = 0;
    if (valid) {
      float bxn = fminf(v0x, fminf(v1x, v2x));
      float byn = fminf(v0y, fminf(v1y, v2y));
      float bxx = fmaxf(v0x, fmaxf(v1x, v2x));
      float byx = fmaxf(v0y, fmaxf(v1y, v2y));
      xmn = (int)floorf(__fmul_rn(__fadd_rn(fminf(fmaxf(bxn,-1.0f),1.0f),1.0f),256.0f));
      ymn = (int)floorf(__fmul_rn(__fadd_rn(fminf(fmaxf(byn,-1.0f),1.0f),1.0f),256.0f));
      xmx = (int)floorf(__fmul_rn(__fadd_rn(fminf(fmaxf(bxx,-1.0f),1.0f),1.0f),256.0f));
      ymx = (int)floorf(__fmul_rn(__fadd_rn(fminf(fmaxf(byx,-1.0f),1.0f),1.0f),256.0f));
    }
    sb[0*NT+t] = (unsigned short)xmn; sb[1*NT+t] = (unsigned short)xmx;
    sb[2*NT+t] = (unsigned short)ymn; sb[3*NT+t] = (unsigned short)ymx;
  }
  float zm = 3.4e38f;
  for (int v = tid; v < NT * 3; v += 256) zm = fminf(zm, tris[v * 3 + 2]);
  for (int off = 32; off > 0; off >>= 1) zm = fminf(zm, __shfl_down(zm, off, 64));
  if ((tid & 63) == 0) s_zred[tid >> 6] = zm;
  __syncthreads();
  zm = fminf(fminf(s_zred[0], s_zred[1]), fminf(s_zred[2], s_zred[3]));
  const int pid = blockIdx.x * 256 + tid;
  const int i = pid >> 9;
  const int j = pid & (TSIZE - 1);
  const float delta = 2.0f / 511.0f;
  const float px = __fadd_rn(-1.0f, __fmul_rn((float)i, delta));
  const float py = __fadd_rn(-1.0f, __fmul_rn((float)j, delta));
  float zb = zm, rx = 0.0f, ry = 0.0f, rz = 0.0f, ra = 0.0f;
  for (int t = 0; t < NT; ++t) {
    int xmn = sb[0*NT+t], xmx = sb[1*NT+t];
    int ymn = sb[2*NT+t], ymx = sb[3*NT+t];
    if (i < xmn || i >= xmx || j < ymn || j >= ymx) continue;
    float v0x = sf[0*NT+t], v0y = sf[1*NT+t];
    float v1x = sf[3*NT+t], v1y = sf[4*NT+t];
    float v2x = sf[6*NT+t], v2y = sf[7*NT+t];
    float pAB = __fsub_rn(__fmul_rn(__fsub_rn(px,v1x), __fsub_rn(v0y,v1y)),
                          __fmul_rn(__fsub_rn(py,v1y), __fsub_rn(v0x,v1x)));
    float pCB = __fsub_rn(__fmul_rn(__fsub_rn(px,v2x), __fsub_rn(v1y,v2y)),
                          __fmul_rn(__fsub_rn(py,v2y), __fsub_rn(v1x,v2x)));
    float pCA = __fsub_rn(__fmul_rn(__fsub_rn(px,v0x), __fsub_rn(v2y,v0y)),
                          __fmul_rn(__fsub_rn(py,v0y), __fsub_rn(v2x,v0x)));
    float prod = __fmul_rn(__fmul_rn(fmaxf(pAB,0.0f), fmaxf(pCB,0.0f)), fmaxf(pCA,0.0f));
    if (prod > 0.0f) {
      float ws = sf[9*NT+t];
      float w1 = __fdiv_rn(pCB, ws);
      float w2 = __fdiv_rn(pCA, ws);
      float w3 = __fsub_rn(__fsub_rn(1.0f, w1), w2);
      float v0z = sf[2*NT+t], v1z = sf[5*NT+t], v2z = sf[8*NT+t];
      float pz = __fadd_rn(__fadd_rn(__fmul_rn(w1,v0z), __fmul_rn(w2,v1z)),
                           __fmul_rn(w3,v2z));
      if (pz >= zb) {
        zb = pz;
        rx = __fadd_rn(__fadd_rn(__fmul_rn(w1,v0x), __fmul_rn(w2,v1x)),
                       __fmul_rn(w3,v2x));
        ry = __fadd_rn(__fadd_rn(__fmul_rn(w1,v0y), __fmul_rn(w2,v1y)),
                       __fmul_rn(w3,v2y));
        rz = pz; ra = 1.0f;
      }
    }
  }
  out[pid] = make_float4(rx, ry, rz, ra);
}

extern "C" void kernel_launch(void* const* d_in, const int* in_sizes, int n_in,
                              void* d_out, int out_size, void* d_ws, size_t ws_size,
                              hipStream_t stream) {
  const float* tris = (const float*)d_in[0];
  float4* out = (float4*)d_out;
  const size_t REC_B  = (size_t)NT * 64;          // 32768
  const size_t BND_B  = (size_t)NT * 8;           // 4096
  const size_t ZMIN_B = 64;
  const size_t KAS_B  = (size_t)NT * 48;          // 24576
  const size_t MASK_B = (size_t)4096 * 8 * 8;     // 262144
  const size_t PART_B = (size_t)2 * NPIX * 8;     // 4 MiB
  const size_t NEED_FULL = REC_B + BND_B + ZMIN_B + KAS_B + MASK_B + PART_B;

  float* recs  = (float*)d_ws;
  uint2* bnds  = (uint2*)((char*)d_ws + REC_B);
  float* zminp = (float*)((char*)d_ws + REC_B + BND_B);
  float* kas   = (float*)((char*)d_ws + REC_B + BND_B + ZMIN_B);
  unsigned long long* masks =
      (unsigned long long*)((char*)d_ws + REC_B + BND_B + ZMIN_B + KAS_B);
  float2* part = (float2*)((char*)d_ws + REC_B + BND_B + ZMIN_B + KAS_B + MASK_B);

  if (ws_size >= NEED_FULL) {
    hipLaunchKernelGGL(render_setup, dim3(1), dim3(NT), 0, stream,
                       tris, recs, bnds, kas, zminp);
    hipLaunchKernelGGL(render_masks, dim3(128), dim3(256), 0, stream,
                       bnds, kas, masks);
    hipLaunchKernelGGL(render_partial, dim3(2048), dim3(256), 0, stream,
                       recs, bnds, masks, zminp, part);
    hipLaunchKernelGGL(render_merge, dim3(NPIX / 256), dim3(256), 0, stream,
                       recs, part, out);
  } else {
    hipLaunchKernelGGL(render_fallback, dim3((TSIZE * TSIZE) / 256), dim3(256), 0, stream,
                       tris, out);
  }
}

// Round 8
// 90.814 us; speedup vs baseline: 1.7654x; 1.0397x over previous
//
#include <hip/hip_runtime.h>

#define TSIZE 512
#define NT 512
#define EPSV 1e-9f
#define NPIX (TSIZE * TSIZE)

// Two kernels only.
// masks : per-(row, 64j-strip) 512-bit survivor bitmask (exact AABB ints +
//         conservative row-slice y-interval via v_rcp). Computes per-tri
//         coeffs in-block (no setup kernel).
// main  : computes all 512 records in-block (coalesced stage -> regs -> LDS),
//         per-pixel loop over mask survivors only (uniform SALU ctz loop,
//         3 evals in flight), tracks (zb, t_win), one exact interp at end.
//
// record (16 floats / 64 B per tri):
//  0: v1x  1: v1y  2: (v0y-v1y)  3: (v0x-v1x)     -> pAB
//  4: v2x  5: v2y  6: (v1y-v2y)  7: (v1x-v2x)     -> pCB
//  8: v0x  9: v0y 10: (v2y-v0y) 11: (v2x-v0x)     -> pCA
// 12: rw=1/ws 13: v2z 14: (v0z-v2z) 15: (v1z-v2z)
// Sign-determining chains are bit-exact vs numpy (__f*_rn, same order);
// interp/z-test deviations are value-only; mask math is conservative-only.

__device__ __forceinline__ float rcp_fast(float x) {
  float r;
  asm("v_rcp_f32 %0, %1" : "=v"(r) : "v"(x));
  return r;
}

// ---------------- masks ----------------
__global__ __launch_bounds__(256) void render_masks(const float* __restrict__ tris,
                                                    unsigned long long* __restrict__ masks) {
  __shared__ float4 raw[1152];        // 18 KB raw tris
  __shared__ float ska[NT * 12];      // 24 KB edge (A,S,K)x3
  __shared__ uint2 sbn[NT];           // 4 KB packed AABB

  const int tid = threadIdx.x;
  {
    const float4* g4 = (const float4*)tris;
#pragma unroll
    for (int k = 0; k < 5; ++k) {
      int idx = tid + 256 * k;
      if (idx < 1152) raw[idx] = g4[idx];
    }
  }
  __syncthreads();
  const float* rawf = (const float*)raw;
#pragma unroll
  for (int q = 0; q < 2; ++q) {
    const int t = 2 * tid + q;
    const float* tp = rawf + t * 9;
    float v0x = tp[0], v0y = tp[1];
    float v1x = tp[3], v1y = tp[4];
    float v2x = tp[6], v2y = tp[7];
    float w = __fsub_rn(__fmul_rn(__fsub_rn(v1x, v0x), __fsub_rn(v2y, v0y)),
                        __fmul_rn(__fsub_rn(v1y, v0y), __fsub_rn(v2x, v0x)));
    bool valid = (w >= EPSV);
    float r2  = __fsub_rn(v0y, v1y), r3  = __fsub_rn(v0x, v1x);
    float r6  = __fsub_rn(v1y, v2y), r7  = __fsub_rn(v1x, v2x);
    float r10 = __fsub_rn(v2y, v0y), r11 = __fsub_rn(v2x, v0x);
    float* ka = &ska[t * 12];
    ka[0] = r2;   ka[1] = -r3;   ka[2] = v1y * r3 - v1x * r2;
    ka[3] = r6;   ka[4] = -r7;   ka[5] = v2y * r7 - v2x * r6;
    ka[6] = r10;  ka[7] = -r11;  ka[8] = v0y * r11 - v0x * r10;
    int xmn = 0, xmx = 0, ymn = 0, ymx = 0;
    if (valid) {
      float bxn = fminf(v0x, fminf(v1x, v2x));
      float byn = fminf(v0y, fminf(v1y, v2y));
      float bxx = fmaxf(v0x, fmaxf(v1x, v2x));
      float byx = fmaxf(v0y, fmaxf(v1y, v2y));
      xmn = (int)floorf(__fmul_rn(__fadd_rn(fminf(fmaxf(bxn, -1.0f), 1.0f), 1.0f), 256.0f));
      ymn = (int)floorf(__fmul_rn(__fadd_rn(fminf(fmaxf(byn, -1.0f), 1.0f), 1.0f), 256.0f));
      xmx = (int)floorf(__fmul_rn(__fadd_rn(fminf(fmaxf(bxx, -1.0f), 1.0f), 1.0f), 256.0f));
      ymx = (int)floorf(__fmul_rn(__fadd_rn(fminf(fmaxf(byx, -1.0f), 1.0f), 1.0f), 256.0f));
    }
    sbn[t] = make_uint2((unsigned)xmn | ((unsigned)xmx << 16),
                        (unsigned)ymn | ((unsigned)ymx << 16));
  }
  __syncthreads();

  const int s = blockIdx.x * 32 + (tid & 31);   // strip 0..4095
  const int w = tid >> 5;                       // word 0..7
  const int i = s >> 3;
  const unsigned jw0 = (unsigned)((s & 7) << 6);
  const float delta = 2.0f / 511.0f;
  const float px  = -1.0f + (float)i * delta;
  const float pyL = -1.0f + (float)jw0 * delta;
  const float pyR = -1.0f + (float)(jw0 + 63u) * delta;

  unsigned long long m = 0;
#pragma unroll 4
  for (int b = 0; b < 64; ++b) {
    const int t = (w << 6) + b;
    uint2 bw = sbn[t];
    unsigned xm = bw.x & 0xFFFFu, xM = bw.x >> 16;
    unsigned ym = bw.y & 0xFFFFu, yM = bw.y >> 16;
    bool pass = ((unsigned)i >= xm) & ((unsigned)i < xM) &
                (ym < jw0 + 64u) & (yM > jw0);
    if (pass) {
      const float4* ka4 = (const float4*)&ska[t * 12];
      float4 e01 = ka4[0];   // A0 S0 K0 A1
      float4 e12 = ka4[1];   // S1 K1 A2 S2
      float4 e2k = ka4[2];   // K2 x x x
      float ylo = -1e30f, yhi = 1e30f;
      {
        float S = e01.y, c = e01.z + e01.x * px;
        if (S > 1e-20f)       { float cd = -c * rcp_fast(S); ylo = fmaxf(ylo, cd - (0.005f + 4e-6f * fabsf(cd))); }
        else if (S < -1e-20f) { float cd = -c * rcp_fast(S); yhi = fminf(yhi, cd + (0.005f + 4e-6f * fabsf(cd))); }
      }
      {
        float S = e12.x, c = e12.y + e01.w * px;
        if (S > 1e-20f)       { float cd = -c * rcp_fast(S); ylo = fmaxf(ylo, cd - (0.005f + 4e-6f * fabsf(cd))); }
        else if (S < -1e-20f) { float cd = -c * rcp_fast(S); yhi = fminf(yhi, cd + (0.005f + 4e-6f * fabsf(cd))); }
      }
      {
        float S = e12.w, c = e2k.x + e12.z * px;
        if (S > 1e-20f)       { float cd = -c * rcp_fast(S); ylo = fmaxf(ylo, cd - (0.005f + 4e-6f * fabsf(cd))); }
        else if (S < -1e-20f) { float cd = -c * rcp_fast(S); yhi = fminf(yhi, cd + (0.005f + 4e-6f * fabsf(cd))); }
      }
      pass = (ylo <= pyR) & (yhi >= pyL);
    }
    m |= ((unsigned long long)(pass ? 1 : 0)) << b;
  }
  masks[(size_t)s * 8 + w] = m;
}

// ---------------- main ----------------
#define EVAL_TRI(c0, c1, c2, c3, yb, tt)                                          \
  do {                                                                            \
    float pAB = __fsub_rn(__fmul_rn(__fsub_rn(px, c0.x), c0.z),                   \
                          __fmul_rn(__fsub_rn(py, c0.y), c0.w));                  \
    float pCB = __fsub_rn(__fmul_rn(__fsub_rn(px, c1.x), c1.z),                   \
                          __fmul_rn(__fsub_rn(py, c1.y), c1.w));                  \
    float pCA = __fsub_rn(__fmul_rn(__fsub_rn(px, c2.x), c2.z),                   \
                          __fmul_rn(__fsub_rn(py, c2.y), c2.w));                  \
    bool ins = (pAB > 0.0f) & (pCB > 0.0f) & (pCA > 0.0f) &                       \
               (ju >= ((yb) & 0xFFFFu)) & (ju < ((yb) >> 16));                    \
    float w1 = __fmul_rn(pCB, c3.x);                                              \
    float w2 = __fmul_rn(pCA, c3.x);                                              \
    float pz = __fmaf_rn(w1, c3.z, __fmaf_rn(w2, c3.w, c3.y));                    \
    bool mk = ins & (pz >= zb);                                                   \
    zb = mk ? pz : zb;                                                            \
    tw = mk ? (tt) : tw;                                                          \
  } while (0)

__global__ __launch_bounds__(256, 4) void render_main(const float* __restrict__ tris,
                                                      const unsigned long long* __restrict__ masks,
                                                      float4* __restrict__ out) {
  __shared__ float4 lrec[NT * 4];   // 32 KB records (first 18 KB reused as raw stage)
  __shared__ unsigned lbY[NT];      // 2 KB  ym|yM<<16
  __shared__ float sred[4];

  const int tid = threadIdx.x;
  // A: coalesced raw stage into lrec area
  {
    float4* rw4 = lrec;
    const float4* g4 = (const float4*)tris;
#pragma unroll
    for (int k = 0; k < 5; ++k) {
      int idx = tid + 256 * k;
      if (idx < 1152) rw4[idx] = g4[idx];
    }
  }
  __syncthreads();
  // B: compute two records into registers
  const float* rawf = (const float*)lrec;
  float rec0[16], rec1[16];
  unsigned yw0, yw1;
  float zp = 3.4e38f;
#pragma unroll
  for (int q = 0; q < 2; ++q) {
    const int t = 2 * tid + q;
    const float* tp = rawf + t * 9;
    float v0x = tp[0], v0y = tp[1], v0z = tp[2];
    float v1x = tp[3], v1y = tp[4], v1z = tp[5];
    float v2x = tp[6], v2y = tp[7], v2z = tp[8];
    zp = fminf(zp, fminf(v0z, fminf(v1z, v2z)));
    float w = __fsub_rn(__fmul_rn(__fsub_rn(v1x, v0x), __fsub_rn(v2y, v0y)),
                        __fmul_rn(__fsub_rn(v1y, v0y), __fsub_rn(v2x, v0x)));
    bool valid = (w >= EPSV);
    float ws = valid ? w : 1.0f;
    float* rr = q ? rec1 : rec0;
    rr[0] = v1x; rr[1] = v1y; rr[2] = __fsub_rn(v0y, v1y); rr[3] = __fsub_rn(v0x, v1x);
    rr[4] = v2x; rr[5] = v2y; rr[6] = __fsub_rn(v1y, v2y); rr[7] = __fsub_rn(v1x, v2x);
    rr[8] = v0x; rr[9] = v0y; rr[10] = __fsub_rn(v2y, v0y); rr[11] = __fsub_rn(v2x, v0x);
    rr[12] = __fdiv_rn(1.0f, ws);
    rr[13] = v2z;
    rr[14] = __fsub_rn(v0z, v2z);
    rr[15] = __fsub_rn(v1z, v2z);
    int xmn = 0, xmx = 0, ymn = 0, ymx = 0;
    if (valid) {
      float bxn = fminf(v0x, fminf(v1x, v2x));
      float byn = fminf(v0y, fminf(v1y, v2y));
      float bxx = fmaxf(v0x, fmaxf(v1x, v2x));
      float byx = fmaxf(v0y, fmaxf(v1y, v2y));
      xmn = (int)floorf(__fmul_rn(__fadd_rn(fminf(fmaxf(bxn, -1.0f), 1.0f), 1.0f), 256.0f));
      ymn = (int)floorf(__fmul_rn(__fadd_rn(fminf(fmaxf(byn, -1.0f), 1.0f), 1.0f), 256.0f));
      xmx = (int)floorf(__fmul_rn(__fadd_rn(fminf(fmaxf(bxx, -1.0f), 1.0f), 1.0f), 256.0f));
      ymx = (int)floorf(__fmul_rn(__fadd_rn(fminf(fmaxf(byx, -1.0f), 1.0f), 1.0f), 256.0f));
    }
    (void)xmn; (void)xmx;
    unsigned yw = (unsigned)ymn | ((unsigned)ymx << 16);
    if (q) yw1 = yw; else yw0 = yw;
  }
  __syncthreads();   // all raw reads done -> safe to overwrite
  // C: write records + zmin reduce
  {
    float4* l4 = lrec;
    const int t0 = 2 * tid, t1 = 2 * tid + 1;
    l4[t0 * 4 + 0] = make_float4(rec0[0], rec0[1], rec0[2], rec0[3]);
    l4[t0 * 4 + 1] = make_float4(rec0[4], rec0[5], rec0[6], rec0[7]);
    l4[t0 * 4 + 2] = make_float4(rec0[8], rec0[9], rec0[10], rec0[11]);
    l4[t0 * 4 + 3] = make_float4(rec0[12], rec0[13], rec0[14], rec0[15]);
    l4[t1 * 4 + 0] = make_float4(rec1[0], rec1[1], rec1[2], rec1[3]);
    l4[t1 * 4 + 1] = make_float4(rec1[4], rec1[5], rec1[6], rec1[7]);
    l4[t1 * 4 + 2] = make_float4(rec1[8], rec1[9], rec1[10], rec1[11]);
    l4[t1 * 4 + 3] = make_float4(rec1[12], rec1[13], rec1[14], rec1[15]);
    lbY[t0] = yw0;
    lbY[t1] = yw1;
    for (int off = 32; off > 0; off >>= 1) zp = fminf(zp, __shfl_down(zp, off, 64));
    if ((tid & 63) == 0) sred[tid >> 6] = zp;
  }
  __syncthreads();
  const float zm0 = fminf(fminf(sred[0], sred[1]), fminf(sred[2], sred[3]));

  const int bb = blockIdx.x;
  const int i = bb >> 1;                       // block-uniform
  const int j = ((bb & 1) << 8) | tid;
  const unsigned ju = (unsigned)j;
  const float delta = 2.0f / 511.0f;
  const float px = __fadd_rn(-1.0f, __fmul_rn((float)i, delta));
  const float py = __fadd_rn(-1.0f, __fmul_rn((float)j, delta));

  // wave-uniform mask row, loaded up-front (single wait, SGPRs)
  const int jstrip = __builtin_amdgcn_readfirstlane(tid >> 6);
  const unsigned long long* mp =
      masks + ((size_t)(i << 3) + ((bb & 1) << 2) + jstrip) * 8;
  unsigned long long m8[8];
#pragma unroll
  for (int k = 0; k < 8; ++k) m8[k] = mp[k];

  float zb = zm0;
  int tw = -1;
  const float4* lr4 = lrec;

#pragma unroll 1
  for (int w = 0; w < 8; ++w) {
    unsigned long long m = m8[w];
    while (m) {
      // pop up to 3 survivors (wave-uniform SALU)
      int t0 = (w << 6) + __builtin_ctzll(m); m &= m - 1;
      int t1 = -1, t2 = -1;
      if (m) {
        t1 = (w << 6) + __builtin_ctzll(m); m &= m - 1;
        if (m) { t2 = (w << 6) + __builtin_ctzll(m); m &= m - 1; }
      }
      // issue all loads, then eval in painter order
      float4 A0 = lr4[t0 * 4 + 0], A1 = lr4[t0 * 4 + 1];
      float4 A2 = lr4[t0 * 4 + 2], A3 = lr4[t0 * 4 + 3];
      unsigned Ay = lbY[t0];
      float4 B0, B1, B2, B3; unsigned By = 0;
      float4 C0, C1, C2, C3; unsigned Cy = 0;
      if (t1 >= 0) {
        B0 = lr4[t1 * 4 + 0]; B1 = lr4[t1 * 4 + 1];
        B2 = lr4[t1 * 4 + 2]; B3 = lr4[t1 * 4 + 3];
        By = lbY[t1];
      }
      if (t2 >= 0) {
        C0 = lr4[t2 * 4 + 0]; C1 = lr4[t2 * 4 + 1];
        C2 = lr4[t2 * 4 + 2]; C3 = lr4[t2 * 4 + 3];
        Cy = lbY[t2];
      }
      EVAL_TRI(A0, A1, A2, A3, Ay, t0);
      if (t1 >= 0) EVAL_TRI(B0, B1, B2, B3, By, t1);
      if (t2 >= 0) EVAL_TRI(C0, C1, C2, C3, Cy, t2);
    }
  }

  float4 res = make_float4(0.0f, 0.0f, 0.0f, 0.0f);
  if (tw >= 0) {
    float4 c1 = lr4[tw * 4 + 1], c2 = lr4[tw * 4 + 2], c3 = lr4[tw * 4 + 3];
    float pCB = __fsub_rn(__fmul_rn(__fsub_rn(px, c1.x), c1.z),
                          __fmul_rn(__fsub_rn(py, c1.y), c1.w));
    float pCA = __fsub_rn(__fmul_rn(__fsub_rn(px, c2.x), c2.z),
                          __fmul_rn(__fsub_rn(py, c2.y), c2.w));
    float w1 = __fmul_rn(pCB, c3.x);
    float w2 = __fmul_rn(pCA, c3.x);
    float rx = __fmaf_rn(w1, -c2.w, __fmaf_rn(w2, c1.w, c1.x));
    float ry = __fmaf_rn(w1, -c2.z, __fmaf_rn(w2, c1.z, c1.y));
    res = make_float4(rx, ry, zb, 1.0f);
  }
  out[(i << 9) | j] = res;
}

// ---- last-resort fallback (round-2 single kernel, no ws) ----
__global__ __launch_bounds__(256) void render_fallback(const float* __restrict__ tris,
                                                       float4* __restrict__ out) {
  __shared__ float sf[10 * NT];
  __shared__ unsigned short sb[4 * NT];
  __shared__ float s_zred[4];
  const int tid = threadIdx.x;
  for (int t = tid; t < NT; t += 256) {
    const float* tp = tris + t * 9;
    float v0x = tp[0], v0y = tp[1], v0z = tp[2];
    float v1x = tp[3], v1y = tp[4], v1z = tp[5];
    float v2x = tp[6], v2y = tp[7], v2z = tp[8];
    sf[0*NT+t] = v0x; sf[1*NT+t] = v0y; sf[2*NT+t] = v0z;
    sf[3*NT+t] = v1x; sf[4*NT+t] = v1y; sf[5*NT+t] = v1z;
    sf[6*NT+t] = v2x; sf[7*NT+t] = v2y; sf[8*NT+t] = v2z;
    float w = __fsub_rn(__fmul_rn(__fsub_rn(v1x,v0x), __fsub_rn(v2y,v0y)),
                        __fmul_rn(__fsub_rn(v1y,v0y), __fsub_rn(v2x,v0x)));
    bool valid = (w >= EPSV);
    sf[9*NT+t] = valid ? w : 1.0f;
    int xmn = 0, xmx = 0, ymn = 0, ymx = 0;
    if (valid) {
      float bxn = fminf(v0x, fminf(v1x, v2x));
      float byn = fminf(v0y, fminf(v1y, v2y));
      float bxx = fmaxf(v0x, fmaxf(v1x, v2x));
      float byx = fmaxf(v0y, fmaxf(v1y, v2y));
      xmn = (int)floorf(__fmul_rn(__fadd_rn(fminf(fmaxf(bxn,-1.0f),1.0f),1.0f),256.0f));
      ymn = (int)floorf(__fmul_rn(__fadd_rn(fminf(fmaxf(byn,-1.0f),1.0f),1.0f),256.0f));
      xmx = (int)floorf(__fmul_rn(__fadd_rn(fminf(fmaxf(bxx,-1.0f),1.0f),1.0f),256.0f));
      ymx = (int)floorf(__fmul_rn(__fadd_rn(fminf(fmaxf(byx,-1.0f),1.0f),1.0f),256.0f));
    }
    sb[0*NT+t] = (unsigned short)xmn; sb[1*NT+t] = (unsigned short)xmx;
    sb[2*NT+t] = (unsigned short)ymn; sb[3*NT+t] = (unsigned short)ymx;
  }
  float zm = 3.4e38f;
  for (int v = tid; v < NT * 3; v += 256) zm = fminf(zm, tris[v * 3 + 2]);
  for (int off = 32; off > 0; off >>= 1) zm = fminf(zm, __shfl_down(zm, off, 64));
  if ((tid & 63) == 0) s_zred[tid >> 6] = zm;
  __syncthreads();
  zm = fminf(fminf(s_zred[0], s_zred[1]), fminf(s_zred[2], s_zred[3]));
  const int pid = blockIdx.x * 256 + tid;
  const int i = pid >> 9;
  const int j = pid & (TSIZE - 1);
  const float delta = 2.0f / 511.0f;
  const float px = __fadd_rn(-1.0f, __fmul_rn((float)i, delta));
  const float py = __fadd_rn(-1.0f, __fmul_rn((float)j, delta));
  float zb = zm, rx = 0.0f, ry = 0.0f, rz = 0.0f, ra = 0.0f;
  for (int t = 0; t < NT; ++t) {
    int xmn = sb[0*NT+t], xmx = sb[1*NT+t];
    int ymn = sb[2*NT+t], ymx = sb[3*NT+t];
    if (i < xmn || i >= xmx || j < ymn || j >= ymx) continue;
    float v0x = sf[0*NT+t], v0y = sf[1*NT+t];
    float v1x = sf[3*NT+t], v1y = sf[4*NT+t];
    float v2x = sf[6*NT+t], v2y = sf[7*NT+t];
    float pAB = __fsub_rn(__fmul_rn(__fsub_rn(px,v1x), __fsub_rn(v0y,v1y)),
                          __fmul_rn(__fsub_rn(py,v1y), __fsub_rn(v0x,v1x)));
    float pCB = __fsub_rn(__fmul_rn(__fsub_rn(px,v2x), __fsub_rn(v1y,v2y)),
                          __fmul_rn(__fsub_rn(py,v2y), __fsub_rn(v1x,v2x)));
    float pCA = __fsub_rn(__fmul_rn(__fsub_rn(px,v0x), __fsub_rn(v2y,v0y)),
                          __fmul_rn(__fsub_rn(py,v0y), __fsub_rn(v2x,v0x)));
    float prod = __fmul_rn(__fmul_rn(fmaxf(pAB,0.0f), fmaxf(pCB,0.0f)), fmaxf(pCA,0.0f));
    if (prod > 0.0f) {
      float ws = sf[9*NT+t];
      float w1 = __fdiv_rn(pCB, ws);
      float w2 = __fdiv_rn(pCA, ws);
      float w3 = __fsub_rn(__fsub_rn(1.0f, w1), w2);
      float v0z = sf[2*NT+t], v1z = sf[5*NT+t], v2z = sf[8*NT+t];
      float pz = __fadd_rn(__fadd_rn(__fmul_rn(w1,v0z), __fmul_rn(w2,v1z)),
                           __fmul_rn(w3,v2z));
      if (pz >= zb) {
        zb = pz;
        rx = __fadd_rn(__fadd_rn(__fmul_rn(w1,v0x), __fmul_rn(w2,v1x)),
                       __fmul_rn(w3,v2x));
        ry = __fadd_rn(__fadd_rn(__fmul_rn(w1,v0y), __fmul_rn(w2,v1y)),
                       __fmul_rn(w3,v2y));
        rz = pz; ra = 1.0f;
      }
    }
  }
  out[pid] = make_float4(rx, ry, rz, ra);
}

extern "C" void kernel_launch(void* const* d_in, const int* in_sizes, int n_in,
                              void* d_out, int out_size, void* d_ws, size_t ws_size,
                              hipStream_t stream) {
  const float* tris = (const float*)d_in[0];
  float4* out = (float4*)d_out;
  const size_t MASK_B = (size_t)4096 * 8 * 8;   // 256 KB

  if (ws_size >= MASK_B) {
    unsigned long long* masks = (unsigned long long*)d_ws;
    hipLaunchKernelGGL(render_masks, dim3(128), dim3(256), 0, stream, tris, masks);
    hipLaunchKernelGGL(render_main, dim3(1024), dim3(256), 0, stream, tris, masks, out);
  } else {
    hipLaunchKernelGGL(render_fallback, dim3((TSIZE * TSIZE) / 256), dim3(256), 0, stream,
                       tris, out);
  }
}

// Round 9
// 89.790 us; speedup vs baseline: 1.7855x; 1.0114x over previous
//
#include <hip/hip_runtime.h>

#define TSIZE 512
#define NT 512
#define EPSV 1e-9f
#define NPIX (TSIZE * TSIZE)

// Two kernels.
// masks : per-(row, 64j-strip) 512-bit survivor bitmask (exact AABB ints +
//         conservative row-slice y-interval via v_rcp). Block 0 additionally
//         writes compact 16-dword per-tri records + zmin to global ws.
// main  : zero LDS. Survivor loop pops 3 uniform tri ids at a time
//         (readfirstlane -> SGPR), records arrive via s_load_dwordx16 (scalar
//         path, no LDS port), evals unconditional in painter order, tracks
//         (zb, t_win). One divergent global-load interp of the winner at end.
//
// compact record (16 floats / 64 B per tri; 11 used):
//  0: v0x 1: v0y 2: v1x 3: v1y 4: v2x 5: v2y
//  6: rw=1/ws 7: v2z 8: (v0z-v2z) 9: (v1z-v2z) 10: yb = ym|yM<<16 (as bits)
// Edge diffs (v0y-v1y etc.) are recomputed per eval with __fsub_rn of the same
// stored values -> bit-identical to the validated R4..R8 chains.
// Sign-determining chains bit-exact vs numpy; mask math conservative-only.

__device__ __forceinline__ float rcp_fast(float x) {
  float r;
  asm("v_rcp_f32 %0, %1" : "=v"(r) : "v"(x));
  return r;
}

// ---------------- masks (+ block0: records, zmin) ----------------
__global__ __launch_bounds__(256) void render_masks(const float* __restrict__ tris,
                                                    unsigned long long* __restrict__ masks,
                                                    float* __restrict__ recs,
                                                    float* __restrict__ zminp) {
  __shared__ float4 raw[1152];        // 18 KB raw tris
  __shared__ float ska[NT * 12];      // 24 KB edge (A,S,K)x3
  __shared__ uint2 sbn[NT];           // 4 KB packed AABB
  __shared__ float sred[4];

  const int tid = threadIdx.x;
  {
    const float4* g4 = (const float4*)tris;
#pragma unroll
    for (int k = 0; k < 5; ++k) {
      int idx = tid + 256 * k;
      if (idx < 1152) raw[idx] = g4[idx];
    }
  }
  __syncthreads();
  const float* rawf = (const float*)raw;
  const bool isb0 = (blockIdx.x == 0);
  float zp = 3.4e38f;
#pragma unroll
  for (int q = 0; q < 2; ++q) {
    const int t = 2 * tid + q;
    const float* tp = rawf + t * 9;
    float v0x = tp[0], v0y = tp[1], v0z = tp[2];
    float v1x = tp[3], v1y = tp[4], v1z = tp[5];
    float v2x = tp[6], v2y = tp[7], v2z = tp[8];
    float w = __fsub_rn(__fmul_rn(__fsub_rn(v1x, v0x), __fsub_rn(v2y, v0y)),
                        __fmul_rn(__fsub_rn(v1y, v0y), __fsub_rn(v2x, v0x)));
    bool valid = (w >= EPSV);
    float r2  = __fsub_rn(v0y, v1y), r3  = __fsub_rn(v0x, v1x);
    float r6  = __fsub_rn(v1y, v2y), r7  = __fsub_rn(v1x, v2x);
    float r10 = __fsub_rn(v2y, v0y), r11 = __fsub_rn(v2x, v0x);
    float* ka = &ska[t * 12];
    ka[0] = r2;   ka[1] = -r3;   ka[2] = v1y * r3 - v1x * r2;
    ka[3] = r6;   ka[4] = -r7;   ka[5] = v2y * r7 - v2x * r6;
    ka[6] = r10;  ka[7] = -r11;  ka[8] = v0y * r11 - v0x * r10;
    int xmn = 0, xmx = 0, ymn = 0, ymx = 0;
    if (valid) {
      float bxn = fminf(v0x, fminf(v1x, v2x));
      float byn = fminf(v0y, fminf(v1y, v2y));
      float bxx = fmaxf(v0x, fmaxf(v1x, v2x));
      float byx = fmaxf(v0y, fmaxf(v1y, v2y));
      xmn = (int)floorf(__fmul_rn(__fadd_rn(fminf(fmaxf(bxn, -1.0f), 1.0f), 1.0f), 256.0f));
      ymn = (int)floorf(__fmul_rn(__fadd_rn(fminf(fmaxf(byn, -1.0f), 1.0f), 1.0f), 256.0f));
      xmx = (int)floorf(__fmul_rn(__fadd_rn(fminf(fmaxf(bxx, -1.0f), 1.0f), 1.0f), 256.0f));
      ymx = (int)floorf(__fmul_rn(__fadd_rn(fminf(fmaxf(byx, -1.0f), 1.0f), 1.0f), 256.0f));
    }
    sbn[t] = make_uint2((unsigned)xmn | ((unsigned)xmx << 16),
                        (unsigned)ymn | ((unsigned)ymx << 16));
    if (isb0) {
      zp = fminf(zp, fminf(v0z, fminf(v1z, v2z)));
      float ws = valid ? w : 1.0f;
      unsigned yw = (unsigned)ymn | ((unsigned)ymx << 16);
      float4* g = (float4*)(recs + ((size_t)t << 4));
      g[0] = make_float4(v0x, v0y, v1x, v1y);
      g[1] = make_float4(v2x, v2y, __fdiv_rn(1.0f, ws), v2z);
      g[2] = make_float4(__fsub_rn(v0z, v2z), __fsub_rn(v1z, v2z),
                         __uint_as_float(yw), 0.0f);
      g[3] = make_float4(0.0f, 0.0f, 0.0f, 0.0f);
    }
  }
  if (isb0) {
    for (int off = 32; off > 0; off >>= 1) zp = fminf(zp, __shfl_down(zp, off, 64));
    if ((tid & 63) == 0) sred[tid >> 6] = zp;
  }
  __syncthreads();
  if (isb0 && tid == 0) {
    zminp[0] = fminf(fminf(sred[0], sred[1]), fminf(sred[2], sred[3]));
  }

  const int s = blockIdx.x * 32 + (tid & 31);   // strip 0..4095
  const int w = tid >> 5;                       // word 0..7
  const int i = s >> 3;
  const unsigned jw0 = (unsigned)((s & 7) << 6);
  const float delta = 2.0f / 511.0f;
  const float px  = -1.0f + (float)i * delta;
  const float pyL = -1.0f + (float)jw0 * delta;
  const float pyR = -1.0f + (float)(jw0 + 63u) * delta;

  unsigned long long m = 0;
#pragma unroll 4
  for (int b = 0; b < 64; ++b) {
    const int t = (w << 6) + b;
    uint2 bw = sbn[t];
    unsigned xm = bw.x & 0xFFFFu, xM = bw.x >> 16;
    unsigned ym = bw.y & 0xFFFFu, yM = bw.y >> 16;
    bool pass = ((unsigned)i >= xm) & ((unsigned)i < xM) &
                (ym < jw0 + 64u) & (yM > jw0);
    if (pass) {
      const float4* ka4 = (const float4*)&ska[t * 12];
      float4 e01 = ka4[0];   // A0 S0 K0 A1
      float4 e12 = ka4[1];   // S1 K1 A2 S2
      float4 e2k = ka4[2];   // K2 x x x
      float ylo = -1e30f, yhi = 1e30f;
      {
        float S = e01.y, c = e01.z + e01.x * px;
        if (S > 1e-20f)       { float cd = -c * rcp_fast(S); ylo = fmaxf(ylo, cd - (0.005f + 4e-6f * fabsf(cd))); }
        else if (S < -1e-20f) { float cd = -c * rcp_fast(S); yhi = fminf(yhi, cd + (0.005f + 4e-6f * fabsf(cd))); }
      }
      {
        float S = e12.x, c = e12.y + e01.w * px;
        if (S > 1e-20f)       { float cd = -c * rcp_fast(S); ylo = fmaxf(ylo, cd - (0.005f + 4e-6f * fabsf(cd))); }
        else if (S < -1e-20f) { float cd = -c * rcp_fast(S); yhi = fminf(yhi, cd + (0.005f + 4e-6f * fabsf(cd))); }
      }
      {
        float S = e12.w, c = e2k.x + e12.z * px;
        if (S > 1e-20f)       { float cd = -c * rcp_fast(S); ylo = fmaxf(ylo, cd - (0.005f + 4e-6f * fabsf(cd))); }
        else if (S < -1e-20f) { float cd = -c * rcp_fast(S); yhi = fminf(yhi, cd + (0.005f + 4e-6f * fabsf(cd))); }
      }
      pass = (ylo <= pyR) & (yhi >= pyL);
    }
    m |= ((unsigned long long)(pass ? 1 : 0)) << b;
  }
  masks[(size_t)s * 8 + w] = m;
}

// ---------------- main ----------------
// Eval one tri from a (uniform) record pointer; diffs recomputed bit-exact.
#define EVAL_T(rp, tt)                                                            \
  do {                                                                            \
    float v0x = (rp)[0], v0y = (rp)[1], v1x = (rp)[2], v1y = (rp)[3];             \
    float v2x = (rp)[4], v2y = (rp)[5];                                           \
    float rw_ = (rp)[6], v2z = (rp)[7], d0z = (rp)[8], d1z = (rp)[9];             \
    unsigned yb = __float_as_uint((rp)[10]);                                      \
    float r2  = __fsub_rn(v0y, v1y), r3  = __fsub_rn(v0x, v1x);                   \
    float r6  = __fsub_rn(v1y, v2y), r7  = __fsub_rn(v1x, v2x);                   \
    float r10 = __fsub_rn(v2y, v0y), r11 = __fsub_rn(v2x, v0x);                   \
    float pAB = __fsub_rn(__fmul_rn(__fsub_rn(px, v1x), r2),                      \
                          __fmul_rn(__fsub_rn(py, v1y), r3));                     \
    float pCB = __fsub_rn(__fmul_rn(__fsub_rn(px, v2x), r6),                      \
                          __fmul_rn(__fsub_rn(py, v2y), r7));                     \
    float pCA = __fsub_rn(__fmul_rn(__fsub_rn(px, v0x), r10),                     \
                          __fmul_rn(__fsub_rn(py, v0y), r11));                    \
    bool ins = (pAB > 0.0f) & (pCB > 0.0f) & (pCA > 0.0f) &                       \
               (ju >= (yb & 0xFFFFu)) & (ju < (yb >> 16));                        \
    float w1 = __fmul_rn(pCB, rw_);                                               \
    float w2 = __fmul_rn(pCA, rw_);                                               \
    float pz = __fmaf_rn(w1, d0z, __fmaf_rn(w2, d1z, v2z));                       \
    bool mk = ins & (pz >= zb);                                                   \
    zb = mk ? pz : zb;                                                            \
    tw = mk ? (tt) : tw;                                                          \
  } while (0)

__global__ __launch_bounds__(256) void render_main(const float* __restrict__ recs,
                                                   const unsigned long long* __restrict__ masks,
                                                   const float* __restrict__ zminp,
                                                   float4* __restrict__ out) {
  const int tid = threadIdx.x;
  const int bb = blockIdx.x;
  const int i = bb >> 1;                       // block-uniform
  const int j = ((bb & 1) << 8) | tid;
  const unsigned ju = (unsigned)j;
  const float delta = 2.0f / 511.0f;
  const float px = __fadd_rn(-1.0f, __fmul_rn((float)i, delta));
  const float py = __fadd_rn(-1.0f, __fmul_rn((float)j, delta));

  // wave-uniform mask row -> scalar loads
  const int jstrip = __builtin_amdgcn_readfirstlane(tid >> 6);
  const unsigned long long* mp =
      masks + ((size_t)(i << 3) + ((bb & 1) << 2) + jstrip) * 8;
  unsigned long long m8[8];
#pragma unroll
  for (int k = 0; k < 8; ++k) m8[k] = mp[k];

  float zb = zminp[0];                          // uniform -> s_load
  int tw = -1;

#pragma unroll 1
  for (int w = 0; w < 8; ++w) {
    unsigned long long m = m8[w];
    while (m) {
      int t0 = (w << 6) + __builtin_ctzll(m); m &= m - 1;
      t0 = __builtin_amdgcn_readfirstlane(t0);
      int t1 = -1, t2 = -1;
      if (m) {
        t1 = (w << 6) + __builtin_ctzll(m); m &= m - 1;
        t1 = __builtin_amdgcn_readfirstlane(t1);
        if (m) {
          t2 = (w << 6) + __builtin_ctzll(m); m &= m - 1;
          t2 = __builtin_amdgcn_readfirstlane(t2);
        }
      }
      const float* r0 = recs + ((size_t)t0 << 4);
      const float* r1 = recs + ((size_t)(t1 < 0 ? t0 : t1) << 4);
      const float* r2p = recs + ((size_t)(t2 < 0 ? t0 : t2) << 4);
      EVAL_T(r0, t0);
      if (t1 >= 0) EVAL_T(r1, t1);
      if (t2 >= 0) EVAL_T(r2p, t2);
    }
  }

  float4 res = make_float4(0.0f, 0.0f, 0.0f, 0.0f);
  if (tw >= 0) {
    // divergent winner -> per-lane vector loads (once per pixel)
    const float4* rr = (const float4*)(recs + ((size_t)tw << 4));
    float4 f0 = rr[0];   // v0x v0y v1x v1y
    float4 f1 = rr[1];   // v2x v2y rw v2z
    float v0x = f0.x, v0y = f0.y, v1x = f0.z, v1y = f0.w;
    float v2x = f1.x, v2y = f1.y, rw_ = f1.z;
    float r6  = __fsub_rn(v1y, v2y), r7  = __fsub_rn(v1x, v2x);
    float r10 = __fsub_rn(v2y, v0y), r11 = __fsub_rn(v2x, v0x);
    float pCB = __fsub_rn(__fmul_rn(__fsub_rn(px, v2x), r6),
                          __fmul_rn(__fsub_rn(py, v2y), r7));
    float pCA = __fsub_rn(__fmul_rn(__fsub_rn(px, v0x), r10),
                          __fmul_rn(__fsub_rn(py, v0y), r11));
    float w1 = __fmul_rn(pCB, rw_);
    float w2 = __fmul_rn(pCA, rw_);
    float rx = __fmaf_rn(w1, -r11, __fmaf_rn(w2, r7, v2x));
    float ry = __fmaf_rn(w1, -r10, __fmaf_rn(w2, r6, v2y));
    res = make_float4(rx, ry, zb, 1.0f);
  }
  out[(i << 9) | j] = res;
}

// ---- last-resort fallback (round-2 single kernel, no ws) ----
__global__ __launch_bounds__(256) void render_fallback(const float* __restrict__ tris,
                                                       float4* __restrict__ out) {
  __shared__ float sf[10 * NT];
  __shared__ unsigned short sb[4 * NT];
  __shared__ float s_zred[4];
  const int tid = threadIdx.x;
  for (int t = tid; t < NT; t += 256) {
    const float* tp = tris + t * 9;
    float v0x = tp[0], v0y = tp[1], v0z = tp[2];
    float v1x = tp[3], v1y = tp[4], v1z = tp[5];
    float v2x = tp[6], v2y = tp[7], v2z = tp[8];
    sf[0*NT+t] = v0x; sf[1*NT+t] = v0y; sf[2*NT+t] = v0z;
    sf[3*NT+t] = v1x; sf[4*NT+t] = v1y; sf[5*NT+t] = v1z;
    sf[6*NT+t] = v2x; sf[7*NT+t] = v2y; sf[8*NT+t] = v2z;
    float w = __fsub_rn(__fmul_rn(__fsub_rn(v1x,v0x), __fsub_rn(v2y,v0y)),
                        __fmul_rn(__fsub_rn(v1y,v0y), __fsub_rn(v2x,v0x)));
    bool valid = (w >= EPSV);
    sf[9*NT+t] = valid ? w : 1.0f;
    int xmn = 0, xmx = 0, ymn = 0, ymx = 0;
    if (valid) {
      float bxn = fminf(v0x, fminf(v1x, v2x));
      float byn = fminf(v0y, fminf(v1y, v2y));
      float bxx = fmaxf(v0x, fmaxf(v1x, v2x));
      float byx = fmaxf(v0y, fmaxf(v1y, v2y));
      xmn = (int)floorf(__fmul_rn(__fadd_rn(fminf(fmaxf(bxn,-1.0f),1.0f),1.0f),256.0f));
      ymn = (int)floorf(__fmul_rn(__fadd_rn(fminf(fmaxf(byn,-1.0f),1.0f),1.0f),256.0f));
      xmx = (int)floorf(__fmul_rn(__fadd_rn(fminf(fmaxf(bxx,-1.0f),1.0f),1.0f),256.0f));
      ymx = (int)floorf(__fmul_rn(__fadd_rn(fminf(fmaxf(byx,-1.0f),1.0f),1.0f),256.0f));
    }
    sb[0*NT+t] = (unsigned short)xmn; sb[1*NT+t] = (unsigned short)xmx;
    sb[2*NT+t] = (unsigned short)ymn; sb[3*NT+t] = (unsigned short)ymx;
  }
  float zm = 3.4e38f;
  for (int v = tid; v < NT * 3; v += 256) zm = fminf(zm, tris[v * 3 + 2]);
  for (int off = 32; off > 0; off >>= 1) zm = fminf(zm, __shfl_down(zm, off, 64));
  if ((tid & 63) == 0) s_zred[tid >> 6] = zm;
  __syncthreads();
  zm = fminf(fminf(s_zred[0], s_zred[1]), fminf(s_zred[2], s_zred[3]));
  const int pid = blockIdx.x * 256 + tid;
  const int i = pid >> 9;
  const int j = pid & (TSIZE - 1);
  const float delta = 2.0f / 511.0f;
  const float px = __fadd_rn(-1.0f, __fmul_rn((float)i, delta));
  const float py = __fadd_rn(-1.0f, __fmul_rn((float)j, delta));
  float zb = zm, rx = 0.0f, ry = 0.0f, rz = 0.0f, ra = 0.0f;
  for (int t = 0; t < NT; ++t) {
    int xmn = sb[0*NT+t], xmx = sb[1*NT+t];
    int ymn = sb[2*NT+t], ymx = sb[3*NT+t];
    if (i < xmn || i >= xmx || j < ymn || j >= ymx) continue;
    float v0x = sf[0*NT+t], v0y = sf[1*NT+t];
    float v1x = sf[3*NT+t], v1y = sf[4*NT+t];
    float v2x = sf[6*NT+t], v2y = sf[7*NT+t];
    float pAB = __fsub_rn(__fmul_rn(__fsub_rn(px,v1x), __fsub_rn(v0y,v1y)),
                          __fmul_rn(__fsub_rn(py,v1y), __fsub_rn(v0x,v1x)));
    float pCB = __fsub_rn(__fmul_rn(__fsub_rn(px,v2x), __fsub_rn(v1y,v2y)),
                          __fmul_rn(__fsub_rn(py,v2y), __fsub_rn(v1x,v2x)));
    float pCA = __fsub_rn(__fmul_rn(__fsub_rn(px,v0x), __fsub_rn(v2y,v0y)),
                          __fmul_rn(__fsub_rn(py,v0y), __fsub_rn(v2x,v0x)));
    float prod = __fmul_rn(__fmul_rn(fmaxf(pAB,0.0f), fmaxf(pCB,0.0f)), fmaxf(pCA,0.0f));
    if (prod > 0.0f) {
      float ws = sf[9*NT+t];
      float w1 = __fdiv_rn(pCB, ws);
      float w2 = __fdiv_rn(pCA, ws);
      float w3 = __fsub_rn(__fsub_rn(1.0f, w1), w2);
      float v0z = sf[2*NT+t], v1z = sf[5*NT+t], v2z = sf[8*NT+t];
      float pz = __fadd_rn(__fadd_rn(__fmul_rn(w1,v0z), __fmul_rn(w2,v1z)),
                           __fmul_rn(w3,v2z));
      if (pz >= zb) {
        zb = pz;
        rx = __fadd_rn(__fadd_rn(__fmul_rn(w1,v0x), __fmul_rn(w2,v1x)),
                       __fmul_rn(w3,v2x));
        ry = __fadd_rn(__fadd_rn(__fmul_rn(w1,v0y), __fmul_rn(w2,v1y)),
                       __fmul_rn(w3,v2y));
        rz = pz; ra = 1.0f;
      }
    }
  }
  out[pid] = make_float4(rx, ry, rz, ra);
}

extern "C" void kernel_launch(void* const* d_in, const int* in_sizes, int n_in,
                              void* d_out, int out_size, void* d_ws, size_t ws_size,
                              hipStream_t stream) {
  const float* tris = (const float*)d_in[0];
  float4* out = (float4*)d_out;
  const size_t REC_B  = (size_t)NT * 64;        // 32 KB
  const size_t MASK_B = (size_t)4096 * 8 * 8;   // 256 KB
  const size_t ZMIN_B = 64;
  const size_t NEED = REC_B + MASK_B + ZMIN_B;

  if (ws_size >= NEED) {
    float* recs = (float*)d_ws;
    unsigned long long* masks = (unsigned long long*)((char*)d_ws + REC_B);
    float* zminp = (float*)((char*)d_ws + REC_B + MASK_B);
    hipLaunchKernelGGL(render_masks, dim3(128), dim3(256), 0, stream,
                       tris, masks, recs, zminp);
    hipLaunchKernelGGL(render_main, dim3(1024), dim3(256), 0, stream,
                       recs, masks, zminp, out);
  } else {
    hipLaunchKernelGGL(render_fallback, dim3((TSIZE * TSIZE) / 256), dim3(256), 0, stream,
                       tris, out);
  }
}